// Round 1
// baseline (1266.361 us; speedup 1.0000x reference)
//
#include <hip/hip_runtime.h>
#include <hip/hip_bf16.h>
#include <cstdint>
#include <cstddef>

// Problem constants
#define NN 20000
#define EE 320000
#define ET (EE + NN)   // edges + self loops

// ---------------------------------------------------------------------------
// Utility: zero an int/float buffer (avoid relying on poisoned ws)
// ---------------------------------------------------------------------------
__global__ void zero_i32(int* __restrict__ p, int n) {
    int i = blockIdx.x * blockDim.x + threadIdx.x;
    if (i < n) p[i] = 0;
}

// ---------------------------------------------------------------------------
// CSR build: count -> scan -> fill   (dst-major CSR, built once per launch)
// ---------------------------------------------------------------------------
__global__ void count_edges(const int* __restrict__ dst, int* __restrict__ cnt) {
    int e = blockIdx.x * blockDim.x + threadIdx.x;
    if (e >= ET) return;
    int d = (e < EE) ? dst[e] : (e - EE);
    atomicAdd(&cnt[d], 1);
}

__global__ void scan20k(const int* __restrict__ cnt, int* __restrict__ rowp,
                        int* __restrict__ wptr, int n) {
    __shared__ int sd[1024];
    __shared__ int run;
    int t = threadIdx.x;
    if (t == 0) run = 0;
    __syncthreads();
    for (int base = 0; base < n; base += 1024) {
        int i = base + t;
        int v = (i < n) ? cnt[i] : 0;
        sd[t] = v;
        __syncthreads();
        for (int o = 1; o < 1024; o <<= 1) {
            int u = (t >= o) ? sd[t - o] : 0;
            __syncthreads();
            sd[t] += u;
            __syncthreads();
        }
        int incl = sd[t];
        int excl = incl - v;
        if (i < n) { int rp = run + excl; rowp[i] = rp; wptr[i] = rp; }
        __syncthreads();                 // everyone done reading `run`
        if (t == 1023) run += sd[1023];  // chunk total
        __syncthreads();
    }
    if (t == 0) rowp[n] = run;
}

__global__ void fill_edges(const int* __restrict__ src, const int* __restrict__ dst,
                           int* __restrict__ wptr, int* __restrict__ colx) {
    int e = blockIdx.x * blockDim.x + threadIdx.x;
    if (e >= ET) return;
    int s, d;
    if (e < EE) { s = src[e]; d = dst[e]; } else { s = e - EE; d = e - EE; }
    int pos = atomicAdd(&wptr[d], 1);
    colx[pos] = s;
}

// ---------------------------------------------------------------------------
// FP32 tiled GEMM: C[M,N] = A[M,K] * B[K,N], 64x64 tile, BK=16, 256 threads,
// 4x4 micro-tile per thread. K % 16 == 0, N % 4 == 0 for all our layers.
// ---------------------------------------------------------------------------
__global__ __launch_bounds__(256) void gemm_f32(const float* __restrict__ A,
                                                const float* __restrict__ B,
                                                float* __restrict__ C,
                                                int M, int N, int K) {
    __shared__ float As[16][65];   // [k][m], +1 pad breaks store conflicts
    __shared__ float Bs[16][64];   // [k][n]
    const int tid = threadIdx.x;
    const int tx = tid & 15, ty = tid >> 4;
    const int row0 = blockIdx.y * 64, col0 = blockIdx.x * 64;
    const int rA = tid >> 2, kq = (tid & 3) << 2;   // A: 64 rows x 4-float k-chunks
    const int rB = tid >> 4, cq = (tid & 15) << 2;  // B: 16 rows x 4-float n-chunks
    float acc[4][4] = {};

    for (int k0 = 0; k0 < K; k0 += 16) {
        float4 fa = make_float4(0.f, 0.f, 0.f, 0.f);
        int arow = row0 + rA;
        if (arow < M) fa = *(const float4*)(A + (size_t)arow * K + k0 + kq);
        float4 fb = make_float4(0.f, 0.f, 0.f, 0.f);
        int bcol = col0 + cq;
        if (bcol < N) fb = *(const float4*)(B + (size_t)(k0 + rB) * N + bcol);
        As[kq + 0][rA] = fa.x; As[kq + 1][rA] = fa.y;
        As[kq + 2][rA] = fa.z; As[kq + 3][rA] = fa.w;
        *(float4*)&Bs[rB][cq] = fb;
        __syncthreads();
#pragma unroll
        for (int k = 0; k < 16; ++k) {
            float a0 = As[k][ty * 4 + 0];
            float a1 = As[k][ty * 4 + 1];
            float a2 = As[k][ty * 4 + 2];
            float a3 = As[k][ty * 4 + 3];
            float4 b = *(float4*)&Bs[k][tx * 4];
            acc[0][0] += a0 * b.x; acc[0][1] += a0 * b.y; acc[0][2] += a0 * b.z; acc[0][3] += a0 * b.w;
            acc[1][0] += a1 * b.x; acc[1][1] += a1 * b.y; acc[1][2] += a1 * b.z; acc[1][3] += a1 * b.w;
            acc[2][0] += a2 * b.x; acc[2][1] += a2 * b.y; acc[2][2] += a2 * b.z; acc[2][3] += a2 * b.w;
            acc[3][0] += a3 * b.x; acc[3][1] += a3 * b.y; acc[3][2] += a3 * b.z; acc[3][3] += a3 * b.w;
        }
        __syncthreads();
    }
#pragma unroll
    for (int i = 0; i < 4; ++i) {
        int r = row0 + ty * 4 + i;
        int c = col0 + tx * 4;
        if (r < M && c < N)
            *(float4*)(C + (size_t)r * N + c) =
                make_float4(acc[i][0], acc[i][1], acc[i][2], acc[i][3]);
    }
}

// ---------------------------------------------------------------------------
// Attention scores: aS[n,h] = <h[n,h,:], att_src[h,:]>, aD likewise.
// One wave per (n, head); lane = channel; shared h load for both dots.
// ---------------------------------------------------------------------------
template <int H, int C>
__global__ void att_scores(const float* __restrict__ h, const float* __restrict__ atts,
                           const float* __restrict__ attd, float* __restrict__ aS,
                           float* __restrict__ aD, int Nn) {
    int wid = (blockIdx.x * blockDim.x + threadIdx.x) >> 6;
    int lane = threadIdx.x & 63;
    int n = wid / H, hh = wid % H;
    if (n >= Nn) return;
    float sv = 0.f, dv = 0.f;
    if (lane < C) {
        float v = h[((size_t)n * H + hh) * C + lane];
        sv = v * atts[hh * C + lane];
        dv = v * attd[hh * C + lane];
    }
#pragma unroll
    for (int o = 32; o > 0; o >>= 1) {
        sv += __shfl_down(sv, o);
        dv += __shfl_down(dv, o);
    }
    if (lane == 0) { aS[n * H + hh] = sv; aD[n * H + hh] = dv; }
}

// ---------------------------------------------------------------------------
// GAT aggregation: one wave per (dst, head).
// Phase 1: online softmax (m, s) over incoming edges, lanes parallel on edges,
//          butterfly combine. Phase 2: serial loop over edges, lane = channel,
//          acc += alpha * h[src, head, lane]. No atomics.
// ---------------------------------------------------------------------------
template <int H, int C>
__global__ void gat_agg(const float* __restrict__ h, const float* __restrict__ aS,
                        const float* __restrict__ aD, const int* __restrict__ rowp,
                        const int* __restrict__ colx, const float* __restrict__ bias,
                        float* __restrict__ out, int Nn) {
    int wid = (blockIdx.x * blockDim.x + threadIdx.x) >> 6;
    int lane = threadIdx.x & 63;
    int n = wid / H, hh = wid % H;
    if (n >= Nn) return;
    int b0 = rowp[n], b1 = rowp[n + 1];
    float adv = aD[n * H + hh];

    // online max/sum (finite sentinel avoids -inf - -inf NaN in combine)
    float m = -1e30f, s = 0.f;
    for (int i = b0 + lane; i < b1; i += 64) {
        int sn = colx[i];
        float e = aS[sn * H + hh] + adv;
        e = (e > 0.f) ? e : 0.2f * e;
        float nm = fmaxf(m, e);
        s = s * __expf(m - nm) + __expf(e - nm);
        m = nm;
    }
#pragma unroll
    for (int o = 32; o > 0; o >>= 1) {
        float mo = __shfl_xor(m, o);
        float so = __shfl_xor(s, o);
        float nm = fmaxf(m, mo);
        s = s * __expf(m - nm) + so * __expf(mo - nm);
        m = nm;
    }
    float inv = 1.f / s;

    float acc = 0.f;
    for (int i = b0; i < b1; ++i) {
        int sn = colx[i];
        float e = aS[sn * H + hh] + adv;
        e = (e > 0.f) ? e : 0.2f * e;
        float al = __expf(e - m) * inv;
        float hv = (lane < C) ? h[((size_t)sn * H + hh) * C + lane] : 0.f;
        acc += al * hv;
    }
    if (lane < C) out[((size_t)n * H + hh) * C + lane] = acc + bias[hh * C + lane];
}

// ---------------------------------------------------------------------------
// BatchNorm stats: per-column sum and sumsq partials, atomicAdd into sums[2F].
// blockDim.x = 128 covers columns (F in {512,256,128}); grid.y chunks rows.
// ---------------------------------------------------------------------------
__global__ void bn_stats(const float* __restrict__ x, float* __restrict__ sums,
                         int Nn, int F) {
    int col = blockIdx.x * blockDim.x + threadIdx.x;
    int r0 = blockIdx.y * 256;
    int r1 = min(r0 + 256, Nn);
    float s = 0.f, q = 0.f;
    for (int r = r0; r < r1; ++r) {
        float v = x[(size_t)r * F + col];
        s += v; q += v * v;
    }
    atomicAdd(&sums[col], s);
    atomicAdd(&sums[F + col], q);
}

// BN apply + ELU, in place. F is a power of two.
__global__ void bn_apply_elu(float* __restrict__ x, const float* __restrict__ sums,
                             const float* __restrict__ gamma, const float* __restrict__ beta,
                             int total, int F, float invN) {
    int i = blockIdx.x * blockDim.x + threadIdx.x;
    if (i >= total) return;
    int c = i & (F - 1);
    float mu = sums[c] * invN;
    float var = sums[F + c] * invN - mu * mu;
    float v = (x[i] - mu) * rsqrtf(var + 1e-5f) * gamma[c] + beta[c];
    x[i] = (v > 0.f) ? v : (__expf(v) - 1.f);
}

// log_softmax over 16 features per node
__global__ void log_softmax16(const float* __restrict__ x, float* __restrict__ out, int Nn) {
    int n = blockIdx.x * blockDim.x + threadIdx.x;
    if (n >= Nn) return;
    float v[16];
    float m = -1e30f;
#pragma unroll
    for (int i = 0; i < 16; ++i) { v[i] = x[n * 16 + i]; m = fmaxf(m, v[i]); }
    float s = 0.f;
#pragma unroll
    for (int i = 0; i < 16; ++i) s += __expf(v[i] - m);
    float l = __logf(s) + m;
#pragma unroll
    for (int i = 0; i < 16; ++i) out[n * 16 + i] = v[i] - l;
}

// ---------------------------------------------------------------------------
// Launcher
// ---------------------------------------------------------------------------
extern "C" void kernel_launch(void* const* d_in, const int* in_sizes, int n_in,
                              void* d_out, int out_size, void* d_ws, size_t ws_size,
                              hipStream_t stream) {
    const float* x   = (const float*)d_in[0];
    const int*   ei  = (const int*)d_in[1];       // [2, E] : row0 = src, row1 = dst
    const float* W1  = (const float*)d_in[2];
    const float* as1 = (const float*)d_in[3];
    const float* ad1 = (const float*)d_in[4];
    const float* b1  = (const float*)d_in[5];
    const float* ga1 = (const float*)d_in[6];
    const float* be1 = (const float*)d_in[7];
    const float* W2  = (const float*)d_in[8];
    const float* as2 = (const float*)d_in[9];
    const float* ad2 = (const float*)d_in[10];
    const float* b2  = (const float*)d_in[11];
    const float* ga2 = (const float*)d_in[12];
    const float* be2 = (const float*)d_in[13];
    const float* W3  = (const float*)d_in[14];
    const float* as3 = (const float*)d_in[15];
    const float* ad3 = (const float*)d_in[16];
    const float* b3  = (const float*)d_in[17];
    const float* ga3 = (const float*)d_in[18];
    const float* be3 = (const float*)d_in[19];
    const float* W4  = (const float*)d_in[20];
    const float* as4 = (const float*)d_in[21];
    const float* ad4 = (const float*)d_in[22];
    const float* b4  = (const float*)d_in[23];
    float* outp = (float*)d_out;

    uint8_t* base = (uint8_t*)d_ws;
    size_t off = 0;
    auto alloc = [&](size_t nbytes) -> void* {
        off = (off + 255) & ~(size_t)255;
        void* p = base + off;
        off += nbytes;
        return p;
    };
    float* bufH = (float*)alloc((size_t)NN * 512 * 4);  // h = x @ W
    float* bufO = (float*)alloc((size_t)NN * 512 * 4);  // aggregated / activations
    float* aS   = (float*)alloc((size_t)NN * 8 * 4);
    float* aD   = (float*)alloc((size_t)NN * 8 * 4);
    int*   cnt  = (int*)alloc((size_t)NN * 4);
    int*   rowp = (int*)alloc((size_t)(NN + 1) * 4);
    int*   wptr = (int*)alloc((size_t)NN * 4);
    int*   colx = (int*)alloc((size_t)ET * 4);
    float* bns  = (float*)alloc((size_t)1024 * 4);      // sums[F] ++ sumsq[F]

    const int* srcRow = ei;
    const int* dstRow = ei + EE;

    // ---- CSR build (once; graph identical every layer) ----
    zero_i32<<<(NN + 255) / 256, 256, 0, stream>>>(cnt, NN);
    count_edges<<<(ET + 255) / 256, 256, 0, stream>>>(dstRow, cnt);
    scan20k<<<1, 1024, 0, stream>>>(cnt, rowp, wptr, NN);
    fill_edges<<<(ET + 255) / 256, 256, 0, stream>>>(srcRow, dstRow, wptr, colx);

    // ---- Layer 1: Fin=512, H=8, C=64 (F=512) ----
    {
        dim3 g((512 + 63) / 64, (NN + 63) / 64);
        gemm_f32<<<g, 256, 0, stream>>>(x, W1, bufH, NN, 512, 512);
        int nw = NN * 8;
        att_scores<8, 64><<<(nw + 3) / 4, 256, 0, stream>>>(bufH, as1, ad1, aS, aD, NN);
        gat_agg<8, 64><<<(nw + 3) / 4, 256, 0, stream>>>(bufH, aS, aD, rowp, colx, b1, bufO, NN);
        zero_i32<<<(1024 + 255) / 256, 256, 0, stream>>>((int*)bns, 1024);
        bn_stats<<<dim3(512 / 128, (NN + 255) / 256), 128, 0, stream>>>(bufO, bns, NN, 512);
        bn_apply_elu<<<((NN * 512) + 255) / 256, 256, 0, stream>>>(bufO, bns, ga1, be1, NN * 512, 512, 1.0f / NN);
    }
    // ---- Layer 2: Fin=512, H=4, C=64 (F=256) ----
    {
        dim3 g((256 + 63) / 64, (NN + 63) / 64);
        gemm_f32<<<g, 256, 0, stream>>>(bufO, W2, bufH, NN, 256, 512);
        int nw = NN * 4;
        att_scores<4, 64><<<(nw + 3) / 4, 256, 0, stream>>>(bufH, as2, ad2, aS, aD, NN);
        gat_agg<4, 64><<<(nw + 3) / 4, 256, 0, stream>>>(bufH, aS, aD, rowp, colx, b2, bufO, NN);
        zero_i32<<<(512 + 255) / 256, 256, 0, stream>>>((int*)bns, 512);
        bn_stats<<<dim3(256 / 128, (NN + 255) / 256), 128, 0, stream>>>(bufO, bns, NN, 256);
        bn_apply_elu<<<((NN * 256) + 255) / 256, 256, 0, stream>>>(bufO, bns, ga2, be2, NN * 256, 256, 1.0f / NN);
    }
    // ---- Layer 3: Fin=256, H=2, C=64 (F=128) ----
    {
        dim3 g((128 + 63) / 64, (NN + 63) / 64);
        gemm_f32<<<g, 256, 0, stream>>>(bufO, W3, bufH, NN, 128, 256);
        int nw = NN * 2;
        att_scores<2, 64><<<(nw + 3) / 4, 256, 0, stream>>>(bufH, as3, ad3, aS, aD, NN);
        gat_agg<2, 64><<<(nw + 3) / 4, 256, 0, stream>>>(bufH, aS, aD, rowp, colx, b3, bufO, NN);
        zero_i32<<<(256 + 255) / 256, 256, 0, stream>>>((int*)bns, 256);
        bn_stats<<<dim3(128 / 128, (NN + 255) / 256), 128, 0, stream>>>(bufO, bns, NN, 128);
        bn_apply_elu<<<((NN * 128) + 255) / 256, 256, 0, stream>>>(bufO, bns, ga3, be3, NN * 128, 128, 1.0f / NN);
    }
    // ---- Layer 4: Fin=128, H=1, C=16 (F=16) + log_softmax ----
    {
        dim3 g((16 + 63) / 64, (NN + 63) / 64);
        gemm_f32<<<g, 256, 0, stream>>>(bufO, W4, bufH, NN, 16, 128);
        int nw = NN * 1;
        att_scores<1, 16><<<(nw + 3) / 4, 256, 0, stream>>>(bufH, as4, ad4, aS, aD, NN);
        gat_agg<1, 16><<<(nw + 3) / 4, 256, 0, stream>>>(bufH, aS, aD, rowp, colx, b4, bufO, NN);
        log_softmax16<<<(NN + 255) / 256, 256, 0, stream>>>(bufO, outp, NN);
    }
}

// Round 2
// 991.469 us; speedup vs baseline: 1.2773x; 1.2773x over previous
//
#include <hip/hip_runtime.h>
#include <hip/hip_bf16.h>
#include <cstdint>
#include <cstddef>

// Problem constants
#define NN 20000
#define EE 320000
#define ET (EE + NN)   // edges + self loops

// ---------------------------------------------------------------------------
// Utility: zero an int/float buffer (avoid relying on poisoned ws)
// ---------------------------------------------------------------------------
__global__ void zero_i32(int* __restrict__ p, int n) {
    int i = blockIdx.x * blockDim.x + threadIdx.x;
    if (i < n) p[i] = 0;
}

// ---------------------------------------------------------------------------
// CSR build: count -> scan -> fill   (dst-major CSR, built once per launch)
// ---------------------------------------------------------------------------
__global__ void count_edges(const int* __restrict__ dst, int* __restrict__ cnt) {
    int e = blockIdx.x * blockDim.x + threadIdx.x;
    if (e >= ET) return;
    int d = (e < EE) ? dst[e] : (e - EE);
    atomicAdd(&cnt[d], 1);
}

__global__ void scan20k(const int* __restrict__ cnt, int* __restrict__ rowp,
                        int* __restrict__ wptr, int n) {
    __shared__ int sd[1024];
    __shared__ int run;
    int t = threadIdx.x;
    if (t == 0) run = 0;
    __syncthreads();
    for (int base = 0; base < n; base += 1024) {
        int i = base + t;
        int v = (i < n) ? cnt[i] : 0;
        sd[t] = v;
        __syncthreads();
        for (int o = 1; o < 1024; o <<= 1) {
            int u = (t >= o) ? sd[t - o] : 0;
            __syncthreads();
            sd[t] += u;
            __syncthreads();
        }
        int incl = sd[t];
        int excl = incl - v;
        if (i < n) { int rp = run + excl; rowp[i] = rp; wptr[i] = rp; }
        __syncthreads();                 // everyone done reading `run`
        if (t == 1023) run += sd[1023];  // chunk total
        __syncthreads();
    }
    if (t == 0) rowp[n] = run;
}

__global__ void fill_edges(const int* __restrict__ src, const int* __restrict__ dst,
                           int* __restrict__ wptr, int* __restrict__ colx) {
    int e = blockIdx.x * blockDim.x + threadIdx.x;
    if (e >= ET) return;
    int s, d;
    if (e < EE) { s = src[e]; d = dst[e]; } else { s = e - EE; d = e - EE; }
    int pos = atomicAdd(&wptr[d], 1);
    colx[pos] = s;
}

// ---------------------------------------------------------------------------
// FP32 tiled GEMM: C[M,N] = A[M,K] * B[K,N], 64x64 tile, BK=16, 256 threads,
// 4x4 micro-tile per thread. K % 16 == 0, N % 4 == 0 for all our layers.
// ---------------------------------------------------------------------------
__global__ __launch_bounds__(256) void gemm_f32(const float* __restrict__ A,
                                                const float* __restrict__ B,
                                                float* __restrict__ C,
                                                int M, int N, int K) {
    __shared__ float As[16][65];   // [k][m], +1 pad breaks store conflicts
    __shared__ float Bs[16][64];   // [k][n]
    const int tid = threadIdx.x;
    const int tx = tid & 15, ty = tid >> 4;
    const int row0 = blockIdx.y * 64, col0 = blockIdx.x * 64;
    const int rA = tid >> 2, kq = (tid & 3) << 2;   // A: 64 rows x 4-float k-chunks
    const int rB = tid >> 4, cq = (tid & 15) << 2;  // B: 16 rows x 4-float n-chunks
    float acc[4][4] = {};

    for (int k0 = 0; k0 < K; k0 += 16) {
        float4 fa = make_float4(0.f, 0.f, 0.f, 0.f);
        int arow = row0 + rA;
        if (arow < M) fa = *(const float4*)(A + (size_t)arow * K + k0 + kq);
        float4 fb = make_float4(0.f, 0.f, 0.f, 0.f);
        int bcol = col0 + cq;
        if (bcol < N) fb = *(const float4*)(B + (size_t)(k0 + rB) * N + bcol);
        As[kq + 0][rA] = fa.x; As[kq + 1][rA] = fa.y;
        As[kq + 2][rA] = fa.z; As[kq + 3][rA] = fa.w;
        *(float4*)&Bs[rB][cq] = fb;
        __syncthreads();
#pragma unroll
        for (int k = 0; k < 16; ++k) {
            float a0 = As[k][ty * 4 + 0];
            float a1 = As[k][ty * 4 + 1];
            float a2 = As[k][ty * 4 + 2];
            float a3 = As[k][ty * 4 + 3];
            float4 b = *(float4*)&Bs[k][tx * 4];
            acc[0][0] += a0 * b.x; acc[0][1] += a0 * b.y; acc[0][2] += a0 * b.z; acc[0][3] += a0 * b.w;
            acc[1][0] += a1 * b.x; acc[1][1] += a1 * b.y; acc[1][2] += a1 * b.z; acc[1][3] += a1 * b.w;
            acc[2][0] += a2 * b.x; acc[2][1] += a2 * b.y; acc[2][2] += a2 * b.z; acc[2][3] += a2 * b.w;
            acc[3][0] += a3 * b.x; acc[3][1] += a3 * b.y; acc[3][2] += a3 * b.z; acc[3][3] += a3 * b.w;
        }
        __syncthreads();
    }
#pragma unroll
    for (int i = 0; i < 4; ++i) {
        int r = row0 + ty * 4 + i;
        int c = col0 + tx * 4;
        if (r < M && c < N)
            *(float4*)(C + (size_t)r * N + c) =
                make_float4(acc[i][0], acc[i][1], acc[i][2], acc[i][3]);
    }
}

// ---------------------------------------------------------------------------
// Attention scores: aS[n,h] = <h[n,h,:], att_src[h,:]>, aD likewise.
// One wave per (n, head); lane = channel; shared h load for both dots.
// ---------------------------------------------------------------------------
template <int H, int C>
__global__ void att_scores(const float* __restrict__ h, const float* __restrict__ atts,
                           const float* __restrict__ attd, float* __restrict__ aS,
                           float* __restrict__ aD, int Nn) {
    int wid = (blockIdx.x * blockDim.x + threadIdx.x) >> 6;
    int lane = threadIdx.x & 63;
    int n = wid / H, hh = wid % H;
    if (n >= Nn) return;
    float sv = 0.f, dv = 0.f;
    if (lane < C) {
        float v = h[((size_t)n * H + hh) * C + lane];
        sv = v * atts[hh * C + lane];
        dv = v * attd[hh * C + lane];
    }
#pragma unroll
    for (int o = 32; o > 0; o >>= 1) {
        sv += __shfl_down(sv, o);
        dv += __shfl_down(dv, o);
    }
    if (lane == 0) { aS[n * H + hh] = sv; aD[n * H + hh] = dv; }
}

// ---------------------------------------------------------------------------
// GAT aggregation, flash-style: one wave per (dst, head).
// Per 64-edge chunk: lane j loads colx/aS ONCE and computes p_j = exp(e_j - m)
// in registers; butterfly max + sum; phase 2 broadcasts (src_j, p_j) via shfl
// (no memory reload, no replicated exp) and gathers h with 4-deep unrolled
// independent loads for ILP. Online rescale across chunks handles any degree.
// ---------------------------------------------------------------------------
template <int H, int C>
__global__ void gat_agg(const float* __restrict__ h, const float* __restrict__ aS,
                        const float* __restrict__ aD, const int* __restrict__ rowp,
                        const int* __restrict__ colx, const float* __restrict__ bias,
                        float* __restrict__ out, int Nn) {
    int wid = (blockIdx.x * blockDim.x + threadIdx.x) >> 6;
    int lane = threadIdx.x & 63;
    int n = wid / H, hh = wid % H;
    if (n >= Nn) return;
    int b0 = rowp[n], b1 = rowp[n + 1];
    float adv = aD[n * H + hh];

    float m = -1e30f, s = 0.f, acc = 0.f;
    for (int c0 = b0; c0 < b1; c0 += 64) {
        int cnt = b1 - c0; if (cnt > 64) cnt = 64;
        int sn = 0; float e = -1e30f;
        if (lane < cnt) {
            sn = colx[c0 + lane];
            float t = aS[sn * H + hh] + adv;
            e = (t > 0.f) ? t : 0.2f * t;
        }
        // chunk max
        float mc = e;
#pragma unroll
        for (int o = 32; o > 0; o >>= 1) mc = fmaxf(mc, __shfl_xor(mc, o));
        float nm = fmaxf(m, mc);
        float sc = __expf(m - nm);       // exp(-huge)=0 on first chunk
        acc *= sc; s *= sc;
        float p = (lane < cnt) ? __expf(e - nm) : 0.f;
        float ps = p;
#pragma unroll
        for (int o = 32; o > 0; o >>= 1) ps += __shfl_xor(ps, o);
        s += ps; m = nm;

        // weighted gather, 4-deep for memory ILP
        int j = 0;
        for (; j + 4 <= cnt; j += 4) {
            int s0 = __shfl(sn, j),     s1 = __shfl(sn, j + 1);
            int s2 = __shfl(sn, j + 2), s3 = __shfl(sn, j + 3);
            float p0 = __shfl(p, j),     p1 = __shfl(p, j + 1);
            float p2 = __shfl(p, j + 2), p3 = __shfl(p, j + 3);
            float h0 = 0.f, h1 = 0.f, h2 = 0.f, h3 = 0.f;
            if (lane < C) {
                h0 = h[((size_t)s0 * H + hh) * C + lane];
                h1 = h[((size_t)s1 * H + hh) * C + lane];
                h2 = h[((size_t)s2 * H + hh) * C + lane];
                h3 = h[((size_t)s3 * H + hh) * C + lane];
            }
            acc += p0 * h0 + p1 * h1 + p2 * h2 + p3 * h3;
        }
        for (; j < cnt; ++j) {
            int sj = __shfl(sn, j);
            float pj = __shfl(p, j);
            float hv = (lane < C) ? h[((size_t)sj * H + hh) * C + lane] : 0.f;
            acc += pj * hv;
        }
    }
    if (lane < C) out[((size_t)n * H + hh) * C + lane] = acc / s + bias[hh * C + lane];
}

// ---------------------------------------------------------------------------
// BatchNorm stats: per-column sum and sumsq partials, atomicAdd into sums[2F].
// ---------------------------------------------------------------------------
__global__ void bn_stats(const float* __restrict__ x, float* __restrict__ sums,
                         int Nn, int F) {
    int col = blockIdx.x * blockDim.x + threadIdx.x;
    int r0 = blockIdx.y * 256;
    int r1 = min(r0 + 256, Nn);
    float s = 0.f, q = 0.f;
    for (int r = r0; r < r1; ++r) {
        float v = x[(size_t)r * F + col];
        s += v; q += v * v;
    }
    atomicAdd(&sums[col], s);
    atomicAdd(&sums[F + col], q);
}

// BN apply + ELU, in place. F is a power of two.
__global__ void bn_apply_elu(float* __restrict__ x, const float* __restrict__ sums,
                             const float* __restrict__ gamma, const float* __restrict__ beta,
                             int total, int F, float invN) {
    int i = blockIdx.x * blockDim.x + threadIdx.x;
    if (i >= total) return;
    int c = i & (F - 1);
    float mu = sums[c] * invN;
    float var = sums[F + c] * invN - mu * mu;
    float v = (x[i] - mu) * rsqrtf(var + 1e-5f) * gamma[c] + beta[c];
    x[i] = (v > 0.f) ? v : (__expf(v) - 1.f);
}

// log_softmax over 16 features per node
__global__ void log_softmax16(const float* __restrict__ x, float* __restrict__ out, int Nn) {
    int n = blockIdx.x * blockDim.x + threadIdx.x;
    if (n >= Nn) return;
    float v[16];
    float m = -1e30f;
#pragma unroll
    for (int i = 0; i < 16; ++i) { v[i] = x[n * 16 + i]; m = fmaxf(m, v[i]); }
    float s = 0.f;
#pragma unroll
    for (int i = 0; i < 16; ++i) s += __expf(v[i] - m);
    float l = __logf(s) + m;
#pragma unroll
    for (int i = 0; i < 16; ++i) out[n * 16 + i] = v[i] - l;
}

// ---------------------------------------------------------------------------
// Launcher
// ---------------------------------------------------------------------------
extern "C" void kernel_launch(void* const* d_in, const int* in_sizes, int n_in,
                              void* d_out, int out_size, void* d_ws, size_t ws_size,
                              hipStream_t stream) {
    const float* x   = (const float*)d_in[0];
    const int*   ei  = (const int*)d_in[1];       // [2, E] : row0 = src, row1 = dst
    const float* W1  = (const float*)d_in[2];
    const float* as1 = (const float*)d_in[3];
    const float* ad1 = (const float*)d_in[4];
    const float* b1  = (const float*)d_in[5];
    const float* ga1 = (const float*)d_in[6];
    const float* be1 = (const float*)d_in[7];
    const float* W2  = (const float*)d_in[8];
    const float* as2 = (const float*)d_in[9];
    const float* ad2 = (const float*)d_in[10];
    const float* b2  = (const float*)d_in[11];
    const float* ga2 = (const float*)d_in[12];
    const float* be2 = (const float*)d_in[13];
    const float* W3  = (const float*)d_in[14];
    const float* as3 = (const float*)d_in[15];
    const float* ad3 = (const float*)d_in[16];
    const float* b3  = (const float*)d_in[17];
    const float* ga3 = (const float*)d_in[18];
    const float* be3 = (const float*)d_in[19];
    const float* W4  = (const float*)d_in[20];
    const float* as4 = (const float*)d_in[21];
    const float* ad4 = (const float*)d_in[22];
    const float* b4  = (const float*)d_in[23];
    float* outp = (float*)d_out;

    uint8_t* base = (uint8_t*)d_ws;
    size_t off = 0;
    auto alloc = [&](size_t nbytes) -> void* {
        off = (off + 255) & ~(size_t)255;
        void* p = base + off;
        off += nbytes;
        return p;
    };
    float* bufH = (float*)alloc((size_t)NN * 512 * 4);  // h = x @ W
    float* bufO = (float*)alloc((size_t)NN * 512 * 4);  // aggregated / activations
    float* aS   = (float*)alloc((size_t)NN * 8 * 4);
    float* aD   = (float*)alloc((size_t)NN * 8 * 4);
    int*   cnt  = (int*)alloc((size_t)NN * 4);
    int*   rowp = (int*)alloc((size_t)(NN + 1) * 4);
    int*   wptr = (int*)alloc((size_t)NN * 4);
    int*   colx = (int*)alloc((size_t)ET * 4);
    float* bns  = (float*)alloc((size_t)1024 * 4);      // sums[F] ++ sumsq[F]

    const int* srcRow = ei;
    const int* dstRow = ei + EE;

    // ---- CSR build (once; graph identical every layer) ----
    zero_i32<<<(NN + 255) / 256, 256, 0, stream>>>(cnt, NN);
    count_edges<<<(ET + 255) / 256, 256, 0, stream>>>(dstRow, cnt);
    scan20k<<<1, 1024, 0, stream>>>(cnt, rowp, wptr, NN);
    fill_edges<<<(ET + 255) / 256, 256, 0, stream>>>(srcRow, dstRow, wptr, colx);

    // ---- Layer 1: Fin=512, H=8, C=64 (F=512) ----
    {
        dim3 g((512 + 63) / 64, (NN + 63) / 64);
        gemm_f32<<<g, 256, 0, stream>>>(x, W1, bufH, NN, 512, 512);
        int nw = NN * 8;
        att_scores<8, 64><<<(nw + 3) / 4, 256, 0, stream>>>(bufH, as1, ad1, aS, aD, NN);
        gat_agg<8, 64><<<(nw + 3) / 4, 256, 0, stream>>>(bufH, aS, aD, rowp, colx, b1, bufO, NN);
        zero_i32<<<(1024 + 255) / 256, 256, 0, stream>>>((int*)bns, 1024);
        bn_stats<<<dim3(512 / 128, (NN + 255) / 256), 128, 0, stream>>>(bufO, bns, NN, 512);
        bn_apply_elu<<<((NN * 512) + 255) / 256, 256, 0, stream>>>(bufO, bns, ga1, be1, NN * 512, 512, 1.0f / NN);
    }
    // ---- Layer 2: Fin=512, H=4, C=64 (F=256) ----
    {
        dim3 g((256 + 63) / 64, (NN + 63) / 64);
        gemm_f32<<<g, 256, 0, stream>>>(bufO, W2, bufH, NN, 256, 512);
        int nw = NN * 4;
        att_scores<4, 64><<<(nw + 3) / 4, 256, 0, stream>>>(bufH, as2, ad2, aS, aD, NN);
        gat_agg<4, 64><<<(nw + 3) / 4, 256, 0, stream>>>(bufH, aS, aD, rowp, colx, b2, bufO, NN);
        zero_i32<<<(512 + 255) / 256, 256, 0, stream>>>((int*)bns, 512);
        bn_stats<<<dim3(256 / 128, (NN + 255) / 256), 128, 0, stream>>>(bufO, bns, NN, 256);
        bn_apply_elu<<<((NN * 256) + 255) / 256, 256, 0, stream>>>(bufO, bns, ga2, be2, NN * 256, 256, 1.0f / NN);
    }
    // ---- Layer 3: Fin=256, H=2, C=64 (F=128) ----
    {
        dim3 g((128 + 63) / 64, (NN + 63) / 64);
        gemm_f32<<<g, 256, 0, stream>>>(bufO, W3, bufH, NN, 128, 256);
        int nw = NN * 2;
        att_scores<2, 64><<<(nw + 3) / 4, 256, 0, stream>>>(bufH, as3, ad3, aS, aD, NN);
        gat_agg<2, 64><<<(nw + 3) / 4, 256, 0, stream>>>(bufH, aS, aD, rowp, colx, b3, bufO, NN);
        zero_i32<<<(256 + 255) / 256, 256, 0, stream>>>((int*)bns, 256);
        bn_stats<<<dim3(128 / 128, (NN + 255) / 256), 128, 0, stream>>>(bufO, bns, NN, 128);
        bn_apply_elu<<<((NN * 128) + 255) / 256, 256, 0, stream>>>(bufO, bns, ga3, be3, NN * 128, 128, 1.0f / NN);
    }
    // ---- Layer 4: Fin=128, H=1, C=16 (F=16) + log_softmax ----
    {
        dim3 g((16 + 63) / 64, (NN + 63) / 64);
        gemm_f32<<<g, 256, 0, stream>>>(bufO, W4, bufH, NN, 16, 128);
        int nw = NN * 1;
        att_scores<1, 16><<<(nw + 3) / 4, 256, 0, stream>>>(bufH, as4, ad4, aS, aD, NN);
        gat_agg<1, 16><<<(nw + 3) / 4, 256, 0, stream>>>(bufH, aS, aD, rowp, colx, b4, bufO, NN);
        log_softmax16<<<(NN + 255) / 256, 256, 0, stream>>>(bufO, outp, NN);
    }
}

// Round 3
// 784.584 us; speedup vs baseline: 1.6141x; 1.2637x over previous
//
#include <hip/hip_runtime.h>
#include <hip/hip_bf16.h>
#include <cstdint>
#include <cstddef>

// Problem constants
#define NN 20000
#define EE 320000
#define ET (EE + NN)     // edges + self loops
#define MPAD 20096       // 157 * 128, M padded to tile

typedef __attribute__((ext_vector_type(8))) short  short8;   // 8 bf16 (4 VGPRs)
typedef __attribute__((ext_vector_type(4))) float  floatx4;  // MFMA C/D frag

// ---------------------------------------------------------------------------
// Utility
// ---------------------------------------------------------------------------
__global__ void zero_i32(int* __restrict__ p, int n) {
    int i = blockIdx.x * blockDim.x + threadIdx.x;
    if (i < n) p[i] = 0;
}

__device__ inline unsigned short f2bf(float f) {   // RNE fp32 -> bf16
    unsigned u = __float_as_uint(f);
    u += 0x7FFFu + ((u >> 16) & 1u);
    return (unsigned short)(u >> 16);
}

// fp32 [M,K] -> bf16 [Mpad,K], rows >= M zero-filled. 4 elems/thread.
__global__ void cvt_a_bf16(const float* __restrict__ in, unsigned short* __restrict__ out,
                           int M, int Mpad, int K) {
    long long base = ((long long)blockIdx.x * blockDim.x + threadIdx.x) * 4;
    if (base >= (long long)Mpad * K) return;
    int row = (int)(base / K);
    float4 v = make_float4(0.f, 0.f, 0.f, 0.f);
    if (row < M) v = *(const float4*)(in + base);
    ushort4 o;
    o.x = f2bf(v.x); o.y = f2bf(v.y); o.z = f2bf(v.z); o.w = f2bf(v.w);
    *(ushort4*)(out + base) = o;
}

// W [K,N] fp32 -> Wt [N,K] bf16 (once per launch; small)
__global__ void cvt_w_t(const float* __restrict__ W, unsigned short* __restrict__ Wt,
                        int K, int N) {
    int i = blockIdx.x * blockDim.x + threadIdx.x;
    if (i >= K * N) return;
    int k = i / N, n = i - k * N;
    Wt[(size_t)n * K + k] = f2bf(W[i]);
}

// ---------------------------------------------------------------------------
// CSR build: count -> scan -> fill   (dst-major CSR, built once per launch)
// ---------------------------------------------------------------------------
__global__ void count_edges(const int* __restrict__ dst, int* __restrict__ cnt) {
    int e = blockIdx.x * blockDim.x + threadIdx.x;
    if (e >= ET) return;
    int d = (e < EE) ? dst[e] : (e - EE);
    atomicAdd(&cnt[d], 1);
}

__global__ void scan20k(const int* __restrict__ cnt, int* __restrict__ rowp,
                        int* __restrict__ wptr, int n) {
    __shared__ int sd[1024];
    __shared__ int run;
    int t = threadIdx.x;
    if (t == 0) run = 0;
    __syncthreads();
    for (int base = 0; base < n; base += 1024) {
        int i = base + t;
        int v = (i < n) ? cnt[i] : 0;
        sd[t] = v;
        __syncthreads();
        for (int o = 1; o < 1024; o <<= 1) {
            int u = (t >= o) ? sd[t - o] : 0;
            __syncthreads();
            sd[t] += u;
            __syncthreads();
        }
        int incl = sd[t];
        int excl = incl - v;
        if (i < n) { int rp = run + excl; rowp[i] = rp; wptr[i] = rp; }
        __syncthreads();
        if (t == 1023) run += sd[1023];
        __syncthreads();
    }
    if (t == 0) rowp[n] = run;
}

__global__ void fill_edges(const int* __restrict__ src, const int* __restrict__ dst,
                           int* __restrict__ wptr, int* __restrict__ colx) {
    int e = blockIdx.x * blockDim.x + threadIdx.x;
    if (e >= ET) return;
    int s, d;
    if (e < EE) { s = src[e]; d = dst[e]; } else { s = e - EE; d = e - EE; }
    int pos = atomicAdd(&wptr[d], 1);
    colx[pos] = s;
}

// ---------------------------------------------------------------------------
// BF16 MFMA GEMM: C[M,N] = A[Mpad,K](bf16) * Bt[N,K](bf16)^T, fp32 out.
// 128x128 block tile, 256 thr = 4 waves (2x2), wave = 64x64 = 4x4 frags of
// 16x16x32. LDS padded to 40 bf16/row (80 B): fragment ds_read_b128 is 2-way
// bank aliased = free. Requires K%32==0, N%128==0, Mpad%128==0.
// ---------------------------------------------------------------------------
__global__ __launch_bounds__(256) void gemm_bf16_mfma(
        const unsigned short* __restrict__ A, const unsigned short* __restrict__ Bt,
        float* __restrict__ C, int M, int N, int K) {
    __shared__ unsigned short As[128][40];
    __shared__ unsigned short Bs[128][40];
    const int t = threadIdx.x;
    const int lane = t & 63, wave = t >> 6;
    const int wm = wave >> 1, wn = wave & 1;
    const int quad = lane >> 4, mrow = lane & 15;
    const int row0 = blockIdx.y * 128, col0 = blockIdx.x * 128;
    const int srow = t >> 2, schunk = (t & 3) * 8;   // staging: 4 chunks x 8 bf16 per row

    floatx4 acc[4][4];
#pragma unroll
    for (int i = 0; i < 4; ++i)
#pragma unroll
        for (int j = 0; j < 4; ++j)
#pragma unroll
            for (int r = 0; r < 4; ++r) acc[i][j][r] = 0.f;

    for (int k0 = 0; k0 < K; k0 += 32) {
        uint4 ra0 = *(const uint4*)(A  + (size_t)(row0 + srow)      * K + k0 + schunk);
        uint4 ra1 = *(const uint4*)(A  + (size_t)(row0 + srow + 64) * K + k0 + schunk);
        uint4 rb0 = *(const uint4*)(Bt + (size_t)(col0 + srow)      * K + k0 + schunk);
        uint4 rb1 = *(const uint4*)(Bt + (size_t)(col0 + srow + 64) * K + k0 + schunk);
        __syncthreads();   // previous iteration's reads done
        *(uint4*)&As[srow][schunk]      = ra0;
        *(uint4*)&As[srow + 64][schunk] = ra1;
        *(uint4*)&Bs[srow][schunk]      = rb0;
        *(uint4*)&Bs[srow + 64][schunk] = rb1;
        __syncthreads();   // stores visible

        short8 af[4], bf[4];
#pragma unroll
        for (int i = 0; i < 4; ++i)
            af[i] = *(const short8*)&As[wm * 64 + i * 16 + mrow][quad * 8];
#pragma unroll
        for (int j = 0; j < 4; ++j)
            bf[j] = *(const short8*)&Bs[wn * 64 + j * 16 + mrow][quad * 8];
#pragma unroll
        for (int i = 0; i < 4; ++i)
#pragma unroll
            for (int j = 0; j < 4; ++j)
                acc[i][j] = __builtin_amdgcn_mfma_f32_16x16x32_bf16(af[i], bf[j], acc[i][j], 0, 0, 0);
    }

    // Epilogue: C/D layout col = lane&15, row = quad*4 + reg
#pragma unroll
    for (int i = 0; i < 4; ++i) {
        int rbase = row0 + wm * 64 + i * 16 + quad * 4;
#pragma unroll
        for (int j = 0; j < 4; ++j) {
            int col = col0 + wn * 64 + j * 16 + mrow;
#pragma unroll
            for (int r = 0; r < 4; ++r) {
                int row = rbase + r;
                if (row < M) C[(size_t)row * N + col] = acc[i][j][r];
            }
        }
    }
}

// ---------------------------------------------------------------------------
// FP32 tiled GEMM (kept for layer 4: N=16)
// ---------------------------------------------------------------------------
__global__ __launch_bounds__(256) void gemm_f32(const float* __restrict__ A,
                                                const float* __restrict__ B,
                                                float* __restrict__ C,
                                                int M, int N, int K) {
    __shared__ float As[16][65];
    __shared__ float Bs[16][64];
    const int tid = threadIdx.x;
    const int tx = tid & 15, ty = tid >> 4;
    const int row0 = blockIdx.y * 64, col0 = blockIdx.x * 64;
    const int rA = tid >> 2, kq = (tid & 3) << 2;
    const int rB = tid >> 4, cq = (tid & 15) << 2;
    float acc[4][4] = {};

    for (int k0 = 0; k0 < K; k0 += 16) {
        float4 fa = make_float4(0.f, 0.f, 0.f, 0.f);
        int arow = row0 + rA;
        if (arow < M) fa = *(const float4*)(A + (size_t)arow * K + k0 + kq);
        float4 fb = make_float4(0.f, 0.f, 0.f, 0.f);
        int bcol = col0 + cq;
        if (bcol < N) fb = *(const float4*)(B + (size_t)(k0 + rB) * N + bcol);
        As[kq + 0][rA] = fa.x; As[kq + 1][rA] = fa.y;
        As[kq + 2][rA] = fa.z; As[kq + 3][rA] = fa.w;
        *(float4*)&Bs[rB][cq] = fb;
        __syncthreads();
#pragma unroll
        for (int k = 0; k < 16; ++k) {
            float a0 = As[k][ty * 4 + 0];
            float a1 = As[k][ty * 4 + 1];
            float a2 = As[k][ty * 4 + 2];
            float a3 = As[k][ty * 4 + 3];
            float4 b = *(float4*)&Bs[k][tx * 4];
            acc[0][0] += a0 * b.x; acc[0][1] += a0 * b.y; acc[0][2] += a0 * b.z; acc[0][3] += a0 * b.w;
            acc[1][0] += a1 * b.x; acc[1][1] += a1 * b.y; acc[1][2] += a1 * b.z; acc[1][3] += a1 * b.w;
            acc[2][0] += a2 * b.x; acc[2][1] += a2 * b.y; acc[2][2] += a2 * b.z; acc[2][3] += a2 * b.w;
            acc[3][0] += a3 * b.x; acc[3][1] += a3 * b.y; acc[3][2] += a3 * b.z; acc[3][3] += a3 * b.w;
        }
        __syncthreads();
    }
#pragma unroll
    for (int i = 0; i < 4; ++i) {
        int r = row0 + ty * 4 + i;
        int c = col0 + tx * 4;
        if (r < M && c < N)
            *(float4*)(C + (size_t)r * N + c) =
                make_float4(acc[i][0], acc[i][1], acc[i][2], acc[i][3]);
    }
}

// ---------------------------------------------------------------------------
// Attention scores: aS[n,h] = <h[n,h,:], att_src[h,:]>, aD likewise.
// ---------------------------------------------------------------------------
template <int H, int C>
__global__ void att_scores(const float* __restrict__ h, const float* __restrict__ atts,
                           const float* __restrict__ attd, float* __restrict__ aS,
                           float* __restrict__ aD, int Nn) {
    int wid = (blockIdx.x * blockDim.x + threadIdx.x) >> 6;
    int lane = threadIdx.x & 63;
    int n = wid / H, hh = wid % H;
    if (n >= Nn) return;
    float sv = 0.f, dv = 0.f;
    if (lane < C) {
        float v = h[((size_t)n * H + hh) * C + lane];
        sv = v * atts[hh * C + lane];
        dv = v * attd[hh * C + lane];
    }
#pragma unroll
    for (int o = 32; o > 0; o >>= 1) {
        sv += __shfl_down(sv, o);
        dv += __shfl_down(dv, o);
    }
    if (lane == 0) { aS[n * H + hh] = sv; aD[n * H + hh] = dv; }
}

// ---------------------------------------------------------------------------
// GAT aggregation, flash-style: one wave per (dst, head).
// ---------------------------------------------------------------------------
template <int H, int C>
__global__ void gat_agg(const float* __restrict__ h, const float* __restrict__ aS,
                        const float* __restrict__ aD, const int* __restrict__ rowp,
                        const int* __restrict__ colx, const float* __restrict__ bias,
                        float* __restrict__ out, int Nn) {
    int wid = (blockIdx.x * blockDim.x + threadIdx.x) >> 6;
    int lane = threadIdx.x & 63;
    int n = wid / H, hh = wid % H;
    if (n >= Nn) return;
    int b0 = rowp[n], b1 = rowp[n + 1];
    float adv = aD[n * H + hh];

    float m = -1e30f, s = 0.f, acc = 0.f;
    for (int c0 = b0; c0 < b1; c0 += 64) {
        int cnt = b1 - c0; if (cnt > 64) cnt = 64;
        int sn = 0; float e = -1e30f;
        if (lane < cnt) {
            sn = colx[c0 + lane];
            float tt = aS[sn * H + hh] + adv;
            e = (tt > 0.f) ? tt : 0.2f * tt;
        }
        float mc = e;
#pragma unroll
        for (int o = 32; o > 0; o >>= 1) mc = fmaxf(mc, __shfl_xor(mc, o));
        float nm = fmaxf(m, mc);
        float sc = __expf(m - nm);
        acc *= sc; s *= sc;
        float p = (lane < cnt) ? __expf(e - nm) : 0.f;
        float ps = p;
#pragma unroll
        for (int o = 32; o > 0; o >>= 1) ps += __shfl_xor(ps, o);
        s += ps; m = nm;

        int j = 0;
        for (; j + 4 <= cnt; j += 4) {
            int s0 = __shfl(sn, j),     s1 = __shfl(sn, j + 1);
            int s2 = __shfl(sn, j + 2), s3 = __shfl(sn, j + 3);
            float p0 = __shfl(p, j),     p1 = __shfl(p, j + 1);
            float p2 = __shfl(p, j + 2), p3 = __shfl(p, j + 3);
            float h0 = 0.f, h1 = 0.f, h2 = 0.f, h3 = 0.f;
            if (lane < C) {
                h0 = h[((size_t)s0 * H + hh) * C + lane];
                h1 = h[((size_t)s1 * H + hh) * C + lane];
                h2 = h[((size_t)s2 * H + hh) * C + lane];
                h3 = h[((size_t)s3 * H + hh) * C + lane];
            }
            acc += p0 * h0 + p1 * h1 + p2 * h2 + p3 * h3;
        }
        for (; j < cnt; ++j) {
            int sj = __shfl(sn, j);
            float pj = __shfl(p, j);
            float hv = (lane < C) ? h[((size_t)sj * H + hh) * C + lane] : 0.f;
            acc += pj * hv;
        }
    }
    if (lane < C) out[((size_t)n * H + hh) * C + lane] = acc / s + bias[hh * C + lane];
}

// ---------------------------------------------------------------------------
// BatchNorm stats + apply, log-softmax
// ---------------------------------------------------------------------------
__global__ void bn_stats(const float* __restrict__ x, float* __restrict__ sums,
                         int Nn, int F) {
    int col = blockIdx.x * blockDim.x + threadIdx.x;
    int r0 = blockIdx.y * 256;
    int r1 = min(r0 + 256, Nn);
    float s = 0.f, q = 0.f;
    for (int r = r0; r < r1; ++r) {
        float v = x[(size_t)r * F + col];
        s += v; q += v * v;
    }
    atomicAdd(&sums[col], s);
    atomicAdd(&sums[F + col], q);
}

__global__ void bn_apply_elu(float* __restrict__ x, const float* __restrict__ sums,
                             const float* __restrict__ gamma, const float* __restrict__ beta,
                             int total, int F, float invN) {
    int i = blockIdx.x * blockDim.x + threadIdx.x;
    if (i >= total) return;
    int c = i & (F - 1);
    float mu = sums[c] * invN;
    float var = sums[F + c] * invN - mu * mu;
    float v = (x[i] - mu) * rsqrtf(var + 1e-5f) * gamma[c] + beta[c];
    x[i] = (v > 0.f) ? v : (__expf(v) - 1.f);
}

__global__ void log_softmax16(const float* __restrict__ x, float* __restrict__ out, int Nn) {
    int n = blockIdx.x * blockDim.x + threadIdx.x;
    if (n >= Nn) return;
    float v[16];
    float m = -1e30f;
#pragma unroll
    for (int i = 0; i < 16; ++i) { v[i] = x[n * 16 + i]; m = fmaxf(m, v[i]); }
    float s = 0.f;
#pragma unroll
    for (int i = 0; i < 16; ++i) s += __expf(v[i] - m);
    float l = __logf(s) + m;
#pragma unroll
    for (int i = 0; i < 16; ++i) out[n * 16 + i] = v[i] - l;
}

// ---------------------------------------------------------------------------
// Launcher
// ---------------------------------------------------------------------------
extern "C" void kernel_launch(void* const* d_in, const int* in_sizes, int n_in,
                              void* d_out, int out_size, void* d_ws, size_t ws_size,
                              hipStream_t stream) {
    const float* x   = (const float*)d_in[0];
    const int*   ei  = (const int*)d_in[1];
    const float* W1  = (const float*)d_in[2];
    const float* as1 = (const float*)d_in[3];
    const float* ad1 = (const float*)d_in[4];
    const float* b1  = (const float*)d_in[5];
    const float* ga1 = (const float*)d_in[6];
    const float* be1 = (const float*)d_in[7];
    const float* W2  = (const float*)d_in[8];
    const float* as2 = (const float*)d_in[9];
    const float* ad2 = (const float*)d_in[10];
    const float* b2  = (const float*)d_in[11];
    const float* ga2 = (const float*)d_in[12];
    const float* be2 = (const float*)d_in[13];
    const float* W3  = (const float*)d_in[14];
    const float* as3 = (const float*)d_in[15];
    const float* ad3 = (const float*)d_in[16];
    const float* b3  = (const float*)d_in[17];
    const float* ga3 = (const float*)d_in[18];
    const float* be3 = (const float*)d_in[19];
    const float* W4  = (const float*)d_in[20];
    const float* as4 = (const float*)d_in[21];
    const float* ad4 = (const float*)d_in[22];
    const float* b4  = (const float*)d_in[23];
    float* outp = (float*)d_out;

    uint8_t* base = (uint8_t*)d_ws;
    size_t off = 0;
    auto alloc = [&](size_t nbytes) -> void* {
        off = (off + 255) & ~(size_t)255;
        void* p = base + off;
        off += nbytes;
        return p;
    };
    float* bufH = (float*)alloc((size_t)NN * 512 * 4);       // GEMM out (fp32)
    float* bufO = (float*)alloc((size_t)NN * 512 * 4);       // aggregated / activations
    unsigned short* bufA = (unsigned short*)alloc((size_t)MPAD * 512 * 2);  // bf16 A
    unsigned short* Wt1  = (unsigned short*)alloc((size_t)512 * 512 * 2);
    unsigned short* Wt2  = (unsigned short*)alloc((size_t)256 * 512 * 2);
    unsigned short* Wt3  = (unsigned short*)alloc((size_t)128 * 256 * 2);
    float* aS   = (float*)alloc((size_t)NN * 8 * 4);
    float* aD   = (float*)alloc((size_t)NN * 8 * 4);
    int*   cnt  = (int*)alloc((size_t)NN * 4);
    int*   rowp = (int*)alloc((size_t)(NN + 1) * 4);
    int*   wptr = (int*)alloc((size_t)NN * 4);
    int*   colx = (int*)alloc((size_t)ET * 4);
    float* bns  = (float*)alloc((size_t)1024 * 4);

    const int* srcRow = ei;
    const int* dstRow = ei + EE;

    // ---- CSR build ----
    zero_i32<<<(NN + 255) / 256, 256, 0, stream>>>(cnt, NN);
    count_edges<<<(ET + 255) / 256, 256, 0, stream>>>(dstRow, cnt);
    scan20k<<<1, 1024, 0, stream>>>(cnt, rowp, wptr, NN);
    fill_edges<<<(ET + 255) / 256, 256, 0, stream>>>(srcRow, dstRow, wptr, colx);

    // ---- Weight transposes+casts (once) ----
    cvt_w_t<<<(512 * 512 + 255) / 256, 256, 0, stream>>>(W1, Wt1, 512, 512);
    cvt_w_t<<<(512 * 256 + 255) / 256, 256, 0, stream>>>(W2, Wt2, 512, 256);
    cvt_w_t<<<(256 * 128 + 255) / 256, 256, 0, stream>>>(W3, Wt3, 256, 128);

    // ---- Layer 1: Fin=512, H=8, C=64 (F=512) ----
    {
        cvt_a_bf16<<<((MPAD * 512 / 4) + 255) / 256, 256, 0, stream>>>(x, bufA, NN, MPAD, 512);
        dim3 g(512 / 128, MPAD / 128);
        gemm_bf16_mfma<<<g, 256, 0, stream>>>(bufA, Wt1, bufH, NN, 512, 512);
        int nw = NN * 8;
        att_scores<8, 64><<<(nw + 3) / 4, 256, 0, stream>>>(bufH, as1, ad1, aS, aD, NN);
        gat_agg<8, 64><<<(nw + 3) / 4, 256, 0, stream>>>(bufH, aS, aD, rowp, colx, b1, bufO, NN);
        zero_i32<<<(1024 + 255) / 256, 256, 0, stream>>>((int*)bns, 1024);
        bn_stats<<<dim3(512 / 128, (NN + 255) / 256), 128, 0, stream>>>(bufO, bns, NN, 512);
        bn_apply_elu<<<((NN * 512) + 255) / 256, 256, 0, stream>>>(bufO, bns, ga1, be1, NN * 512, 512, 1.0f / NN);
    }
    // ---- Layer 2: Fin=512, H=4, C=64 (F=256) ----
    {
        cvt_a_bf16<<<((MPAD * 512 / 4) + 255) / 256, 256, 0, stream>>>(bufO, bufA, NN, MPAD, 512);
        dim3 g(256 / 128, MPAD / 128);
        gemm_bf16_mfma<<<g, 256, 0, stream>>>(bufA, Wt2, bufH, NN, 256, 512);
        int nw = NN * 4;
        att_scores<4, 64><<<(nw + 3) / 4, 256, 0, stream>>>(bufH, as2, ad2, aS, aD, NN);
        gat_agg<4, 64><<<(nw + 3) / 4, 256, 0, stream>>>(bufH, aS, aD, rowp, colx, b2, bufO, NN);
        zero_i32<<<(512 + 255) / 256, 256, 0, stream>>>((int*)bns, 512);
        bn_stats<<<dim3(256 / 128, (NN + 255) / 256), 128, 0, stream>>>(bufO, bns, NN, 256);
        bn_apply_elu<<<((NN * 256) + 255) / 256, 256, 0, stream>>>(bufO, bns, ga2, be2, NN * 256, 256, 1.0f / NN);
    }
    // ---- Layer 3: Fin=256, H=2, C=64 (F=128) ----
    {
        cvt_a_bf16<<<((MPAD * 256 / 4) + 255) / 256, 256, 0, stream>>>(bufO, bufA, NN, MPAD, 256);
        dim3 g(128 / 128, MPAD / 128);
        gemm_bf16_mfma<<<g, 256, 0, stream>>>(bufA, Wt3, bufH, NN, 128, 256);
        int nw = NN * 2;
        att_scores<2, 64><<<(nw + 3) / 4, 256, 0, stream>>>(bufH, as3, ad3, aS, aD, NN);
        gat_agg<2, 64><<<(nw + 3) / 4, 256, 0, stream>>>(bufH, aS, aD, rowp, colx, b3, bufO, NN);
        zero_i32<<<(256 + 255) / 256, 256, 0, stream>>>((int*)bns, 256);
        bn_stats<<<dim3(128 / 128, (NN + 255) / 256), 128, 0, stream>>>(bufO, bns, NN, 128);
        bn_apply_elu<<<((NN * 128) + 255) / 256, 256, 0, stream>>>(bufO, bns, ga3, be3, NN * 128, 128, 1.0f / NN);
    }
    // ---- Layer 4: Fin=128, H=1, C=16 (F=16) + log_softmax ----
    {
        dim3 g((16 + 63) / 64, (NN + 63) / 64);
        gemm_f32<<<g, 256, 0, stream>>>(bufO, W4, bufH, NN, 16, 128);
        int nw = NN * 1;
        att_scores<1, 16><<<(nw + 3) / 4, 256, 0, stream>>>(bufH, as4, ad4, aS, aD, NN);
        gat_agg<1, 16><<<(nw + 3) / 4, 256, 0, stream>>>(bufH, aS, aD, rowp, colx, b4, bufO, NN);
        log_softmax16<<<(NN + 255) / 256, 256, 0, stream>>>(bufO, outp, NN);
    }
}

// Round 4
// 749.176 us; speedup vs baseline: 1.6903x; 1.0473x over previous
//
#include <hip/hip_runtime.h>
#include <hip/hip_bf16.h>
#include <cstdint>
#include <cstddef>

// Problem constants
#define NN 20000
#define EE 320000
#define ET (EE + NN)     // edges + self loops
#define MPAD 20096       // 157 * 128, M padded to tile
#define PCHUNK 79        // ceil(20000/256) row chunks for BN partials

typedef __attribute__((ext_vector_type(8))) short  short8;   // 8 bf16 (4 VGPRs)
typedef __attribute__((ext_vector_type(4))) float  floatx4;  // MFMA C/D frag

// ---------------------------------------------------------------------------
// Utility
// ---------------------------------------------------------------------------
__global__ void zero_i32(int* __restrict__ p, int n) {
    int i = blockIdx.x * blockDim.x + threadIdx.x;
    if (i < n) p[i] = 0;
}

__device__ inline unsigned short f2bf(float f) {   // RNE fp32 -> bf16
    unsigned u = __float_as_uint(f);
    u += 0x7FFFu + ((u >> 16) & 1u);
    return (unsigned short)(u >> 16);
}
__device__ inline float bf2f(unsigned short b) {
    return __uint_as_float(((unsigned)b) << 16);
}

// fp32 [M,K] -> bf16 [Mpad,K], rows >= M zero-filled. 4 elems/thread.
__global__ void cvt_a_bf16(const float* __restrict__ in, unsigned short* __restrict__ out,
                           int M, int Mpad, int K) {
    long long base = ((long long)blockIdx.x * blockDim.x + threadIdx.x) * 4;
    if (base >= (long long)Mpad * K) return;
    int row = (int)(base / K);
    float4 v = make_float4(0.f, 0.f, 0.f, 0.f);
    if (row < M) v = *(const float4*)(in + base);
    ushort4 o;
    o.x = f2bf(v.x); o.y = f2bf(v.y); o.z = f2bf(v.z); o.w = f2bf(v.w);
    *(ushort4*)(out + base) = o;
}

// W [K,N] fp32 -> Wt [N,K] bf16 (once per launch; small)
__global__ void cvt_w_t(const float* __restrict__ W, unsigned short* __restrict__ Wt,
                        int K, int N) {
    int i = blockIdx.x * blockDim.x + threadIdx.x;
    if (i >= K * N) return;
    int k = i / N, n = i - k * N;
    Wt[(size_t)n * K + k] = f2bf(W[i]);
}

// ---------------------------------------------------------------------------
// CSR build: count -> scan -> fill   (dst-major CSR, built once per launch)
// ---------------------------------------------------------------------------
__global__ void count_edges(const int* __restrict__ dst, int* __restrict__ cnt) {
    int e = blockIdx.x * blockDim.x + threadIdx.x;
    if (e >= ET) return;
    int d = (e < EE) ? dst[e] : (e - EE);
    atomicAdd(&cnt[d], 1);
}

__global__ void scan20k(const int* __restrict__ cnt, int* __restrict__ rowp,
                        int* __restrict__ wptr, int n) {
    __shared__ int sd[1024];
    __shared__ int run;
    int t = threadIdx.x;
    if (t == 0) run = 0;
    __syncthreads();
    for (int base = 0; base < n; base += 1024) {
        int i = base + t;
        int v = (i < n) ? cnt[i] : 0;
        sd[t] = v;
        __syncthreads();
        for (int o = 1; o < 1024; o <<= 1) {
            int u = (t >= o) ? sd[t - o] : 0;
            __syncthreads();
            sd[t] += u;
            __syncthreads();
        }
        int incl = sd[t];
        int excl = incl - v;
        if (i < n) { int rp = run + excl; rowp[i] = rp; wptr[i] = rp; }
        __syncthreads();
        if (t == 1023) run += sd[1023];
        __syncthreads();
    }
    if (t == 0) rowp[n] = run;
}

__global__ void fill_edges(const int* __restrict__ src, const int* __restrict__ dst,
                           int* __restrict__ wptr, int* __restrict__ colx) {
    int e = blockIdx.x * blockDim.x + threadIdx.x;
    if (e >= ET) return;
    int s, d;
    if (e < EE) { s = src[e]; d = dst[e]; } else { s = e - EE; d = e - EE; }
    int pos = atomicAdd(&wptr[d], 1);
    colx[pos] = s;
}

// ---------------------------------------------------------------------------
// BF16 MFMA GEMM with fused epilogue:
//   - writes hT[head][row][c] in bf16 (head-major, C=64 channels/head)
//   - computes aSt[head][row], aDt[head][row] (attention dots) in-register
// C[M,N] = A[Mpad,K] * Bt[N,K]^T. 128x128 tile, 4 waves, 16x16x32 MFMA.
// Each wave's fragments cover 64 rows x 64 cols = 64 rows x 1 full head.
// Requires K%32==0, N%128==0, N multiple of 64 aligned heads (C=64).
// ---------------------------------------------------------------------------
__global__ __launch_bounds__(256) void gemm_bf16_fused(
        const unsigned short* __restrict__ A, const unsigned short* __restrict__ Bt,
        unsigned short* __restrict__ hT, float* __restrict__ aSt, float* __restrict__ aDt,
        const float* __restrict__ atts, const float* __restrict__ attd,
        int M, int N, int K, int Nn) {
    __shared__ unsigned short As[128][40];
    __shared__ unsigned short Bs[128][40];
    const int t = threadIdx.x;
    const int lane = t & 63, wave = t >> 6;
    const int wm = wave >> 1, wn = wave & 1;
    const int quad = lane >> 4, mrow = lane & 15;
    const int row0 = blockIdx.y * 128, col0 = blockIdx.x * 128;
    const int srow = t >> 2, schunk = (t & 3) * 8;

    floatx4 acc[4][4];
#pragma unroll
    for (int i = 0; i < 4; ++i)
#pragma unroll
        for (int j = 0; j < 4; ++j)
#pragma unroll
            for (int r = 0; r < 4; ++r) acc[i][j][r] = 0.f;

    for (int k0 = 0; k0 < K; k0 += 32) {
        uint4 ra0 = *(const uint4*)(A  + (size_t)(row0 + srow)      * K + k0 + schunk);
        uint4 ra1 = *(const uint4*)(A  + (size_t)(row0 + srow + 64) * K + k0 + schunk);
        uint4 rb0 = *(const uint4*)(Bt + (size_t)(col0 + srow)      * K + k0 + schunk);
        uint4 rb1 = *(const uint4*)(Bt + (size_t)(col0 + srow + 64) * K + k0 + schunk);
        __syncthreads();
        *(uint4*)&As[srow][schunk]      = ra0;
        *(uint4*)&As[srow + 64][schunk] = ra1;
        *(uint4*)&Bs[srow][schunk]      = rb0;
        *(uint4*)&Bs[srow + 64][schunk] = rb1;
        __syncthreads();

        short8 af[4], bfr[4];
#pragma unroll
        for (int i = 0; i < 4; ++i)
            af[i] = *(const short8*)&As[wm * 64 + i * 16 + mrow][quad * 8];
#pragma unroll
        for (int j = 0; j < 4; ++j)
            bfr[j] = *(const short8*)&Bs[wn * 64 + j * 16 + mrow][quad * 8];
#pragma unroll
        for (int i = 0; i < 4; ++i)
#pragma unroll
            for (int j = 0; j < 4; ++j)
                acc[i][j] = __builtin_amdgcn_mfma_f32_16x16x32_bf16(af[i], bfr[j], acc[i][j], 0, 0, 0);
    }

    // ---- fused epilogue ----
    // wave covers rows [row0+wm*64, +64), head = (col0 + wn*64)/64, cols c=j*16+mrow
    const int head = (col0 + wn * 64) >> 6;
    float attS[4], attD[4];
#pragma unroll
    for (int j = 0; j < 4; ++j) {
        attS[j] = atts[head * 64 + j * 16 + mrow];
        attD[j] = attd[head * 64 + j * 16 + mrow];
    }
    unsigned short* ht = hT + (size_t)head * Nn * 64;

#pragma unroll
    for (int i = 0; i < 4; ++i) {
#pragma unroll
        for (int r = 0; r < 4; ++r) {
            int row = row0 + wm * 64 + i * 16 + quad * 4 + r;
            // attention dots: partial over j, butterfly over mrow (within quad)
            float ps = acc[i][0][r] * attS[0] + acc[i][1][r] * attS[1]
                     + acc[i][2][r] * attS[2] + acc[i][3][r] * attS[3];
            float pd = acc[i][0][r] * attD[0] + acc[i][1][r] * attD[1]
                     + acc[i][2][r] * attD[2] + acc[i][3][r] * attD[3];
#pragma unroll
            for (int o = 1; o < 16; o <<= 1) {
                ps += __shfl_xor(ps, o);
                pd += __shfl_xor(pd, o);
            }
            if (row < M) {
                if (mrow == 0) {
                    aSt[head * Nn + row] = ps;
                    aDt[head * Nn + row] = pd;
                }
                // h store: bf16, head-major
#pragma unroll
                for (int j = 0; j < 4; ++j)
                    ht[(size_t)row * 64 + j * 16 + mrow] = f2bf(acc[i][j][r]);
            }
        }
    }
}

// ---------------------------------------------------------------------------
// FP32 tiled GEMM for layer 4 (N=16) -> writes bf16 hT (single head, C=16)
// ---------------------------------------------------------------------------
__global__ __launch_bounds__(256) void gemm_f32_bf16out(const float* __restrict__ A,
                                                        const float* __restrict__ B,
                                                        unsigned short* __restrict__ C,
                                                        int M, int N, int K) {
    __shared__ float As[16][65];
    __shared__ float Bs[16][64];
    const int tid = threadIdx.x;
    const int tx = tid & 15, ty = tid >> 4;
    const int row0 = blockIdx.y * 64, col0 = blockIdx.x * 64;
    const int rA = tid >> 2, kq = (tid & 3) << 2;
    const int rB = tid >> 4, cq = (tid & 15) << 2;
    float acc[4][4] = {};

    for (int k0 = 0; k0 < K; k0 += 16) {
        float4 fa = make_float4(0.f, 0.f, 0.f, 0.f);
        int arow = row0 + rA;
        if (arow < M) fa = *(const float4*)(A + (size_t)arow * K + k0 + kq);
        float4 fb = make_float4(0.f, 0.f, 0.f, 0.f);
        int bcol = col0 + cq;
        if (bcol < N) fb = *(const float4*)(B + (size_t)(k0 + rB) * N + bcol);
        As[kq + 0][rA] = fa.x; As[kq + 1][rA] = fa.y;
        As[kq + 2][rA] = fa.z; As[kq + 3][rA] = fa.w;
        *(float4*)&Bs[rB][cq] = fb;
        __syncthreads();
#pragma unroll
        for (int k = 0; k < 16; ++k) {
            float a0 = As[k][ty * 4 + 0];
            float a1 = As[k][ty * 4 + 1];
            float a2 = As[k][ty * 4 + 2];
            float a3 = As[k][ty * 4 + 3];
            float4 b = *(float4*)&Bs[k][tx * 4];
            acc[0][0] += a0 * b.x; acc[0][1] += a0 * b.y; acc[0][2] += a0 * b.z; acc[0][3] += a0 * b.w;
            acc[1][0] += a1 * b.x; acc[1][1] += a1 * b.y; acc[1][2] += a1 * b.z; acc[1][3] += a1 * b.w;
            acc[2][0] += a2 * b.x; acc[2][1] += a2 * b.y; acc[2][2] += a2 * b.z; acc[2][3] += a2 * b.w;
            acc[3][0] += a3 * b.x; acc[3][1] += a3 * b.y; acc[3][2] += a3 * b.z; acc[3][3] += a3 * b.w;
        }
        __syncthreads();
    }
#pragma unroll
    for (int i = 0; i < 4; ++i) {
        int r = row0 + ty * 4 + i;
        if (r >= M) continue;
#pragma unroll
        for (int jj = 0; jj < 4; ++jj) {
            int c = col0 + tx * 4 + jj;
            if (c < N) C[(size_t)r * N + c] = f2bf(acc[i][jj]);
        }
    }
}

// ---------------------------------------------------------------------------
// Attention scores from bf16 h (layer 4 only): one wave per node, H=1.
// ---------------------------------------------------------------------------
template <int C>
__global__ void att_scores_bf(const unsigned short* __restrict__ h,
                              const float* __restrict__ atts, const float* __restrict__ attd,
                              float* __restrict__ aS, float* __restrict__ aD, int Nn) {
    int wid = (blockIdx.x * blockDim.x + threadIdx.x) >> 6;
    int lane = threadIdx.x & 63;
    if (wid >= Nn) return;
    float sv = 0.f, dv = 0.f;
    if (lane < C) {
        float v = bf2f(h[(size_t)wid * C + lane]);
        sv = v * atts[lane];
        dv = v * attd[lane];
    }
#pragma unroll
    for (int o = 32; o > 0; o >>= 1) {
        sv += __shfl_down(sv, o);
        dv += __shfl_down(dv, o);
    }
    if (lane == 0) { aS[wid] = sv; aD[wid] = dv; }
}

// ---------------------------------------------------------------------------
// GAT aggregation, flash-style, bf16 gathers, head-major tables.
// Block b: head = b % H (XCD-affinity heuristic), 4 waves = 4 dst nodes.
// Output layout [N][H*C] fp32 (BN layout).
// ---------------------------------------------------------------------------
template <int H, int C>
__global__ void gat_agg_bf(const unsigned short* __restrict__ hT,
                           const float* __restrict__ aSt, const float* __restrict__ aDt,
                           const int* __restrict__ rowp, const int* __restrict__ colx,
                           const float* __restrict__ bias, float* __restrict__ out, int Nn) {
    int b = blockIdx.x;
    int head = b % H;
    int n = (b / H) * 4 + (threadIdx.x >> 6);
    int lane = threadIdx.x & 63;
    if (n >= Nn) return;
    const unsigned short* ht = hT + (size_t)head * Nn * C;
    const float* as = aSt + (size_t)head * Nn;
    float adv = aDt[(size_t)head * Nn + n];
    int b0 = rowp[n], b1 = rowp[n + 1];

    float m = -1e30f, s = 0.f, acc = 0.f;
    for (int c0 = b0; c0 < b1; c0 += 64) {
        int cnt = b1 - c0; if (cnt > 64) cnt = 64;
        int sn = 0; float e = -1e30f;
        if (lane < cnt) {
            sn = colx[c0 + lane];
            float tt = as[sn] + adv;
            e = (tt > 0.f) ? tt : 0.2f * tt;
        }
        float mc = e;
#pragma unroll
        for (int o = 32; o > 0; o >>= 1) mc = fmaxf(mc, __shfl_xor(mc, o));
        float nm = fmaxf(m, mc);
        float sc = __expf(m - nm);
        acc *= sc; s *= sc;
        float p = (lane < cnt) ? __expf(e - nm) : 0.f;
        float ps = p;
#pragma unroll
        for (int o = 32; o > 0; o >>= 1) ps += __shfl_xor(ps, o);
        s += ps; m = nm;

        int j = 0;
        for (; j + 4 <= cnt; j += 4) {
            int s0 = __shfl(sn, j),     s1 = __shfl(sn, j + 1);
            int s2 = __shfl(sn, j + 2), s3 = __shfl(sn, j + 3);
            float p0 = __shfl(p, j),     p1 = __shfl(p, j + 1);
            float p2 = __shfl(p, j + 2), p3 = __shfl(p, j + 3);
            float h0 = 0.f, h1 = 0.f, h2 = 0.f, h3 = 0.f;
            if (lane < C) {
                h0 = bf2f(ht[(size_t)s0 * C + lane]);
                h1 = bf2f(ht[(size_t)s1 * C + lane]);
                h2 = bf2f(ht[(size_t)s2 * C + lane]);
                h3 = bf2f(ht[(size_t)s3 * C + lane]);
            }
            acc += p0 * h0 + p1 * h1 + p2 * h2 + p3 * h3;
        }
        for (; j < cnt; ++j) {
            int sj = __shfl(sn, j);
            float pj = __shfl(p, j);
            float hv = (lane < C) ? bf2f(ht[(size_t)sj * C + lane]) : 0.f;
            acc += pj * hv;
        }
    }
    if (lane < C)
        out[(size_t)n * (H * C) + head * C + lane] = acc / s + bias[head * C + lane];
}

// ---------------------------------------------------------------------------
// BatchNorm: partial stats (no atomics) -> finalize (scale/shift) -> apply+ELU
// writing bf16 directly into the next GEMM's padded A buffer.
// ---------------------------------------------------------------------------
__global__ void bn_stats_part(const float* __restrict__ x, float* __restrict__ part,
                              int Nn, int F) {
    int col = blockIdx.x * blockDim.x + threadIdx.x;
    int r0 = blockIdx.y * 256;
    int r1 = min(r0 + 256, Nn);
    float s = 0.f, q = 0.f;
    for (int r = r0; r < r1; ++r) {
        float v = x[(size_t)r * F + col];
        s += v; q += v * v;
    }
    part[(size_t)blockIdx.y * 2 * F + col] = s;
    part[(size_t)blockIdx.y * 2 * F + F + col] = q;
}

__global__ void bn_finalize(const float* __restrict__ part, const float* __restrict__ gamma,
                            const float* __restrict__ beta, float* __restrict__ ss,
                            int F, int P, float invN) {
    int c = threadIdx.x;
    if (c >= F) return;
    float s = 0.f, q = 0.f;
    for (int p = 0; p < P; ++p) {
        s += part[(size_t)p * 2 * F + c];
        q += part[(size_t)p * 2 * F + F + c];
    }
    float mu = s * invN;
    float var = q * invN - mu * mu;
    float sc = gamma[c] * rsqrtf(var + 1e-5f);
    ss[c] = sc;
    ss[F + c] = beta[c] - mu * sc;
}

// x [Nn,F] fp32 -> bufA [Mpad,F] bf16 with BN+ELU; rows>=Nn zeroed. 4/thread.
__global__ void bn_apply_elu_bf16(const float* __restrict__ x, const float* __restrict__ ss,
                                  unsigned short* __restrict__ outA,
                                  int Nn, int F, int fmask) {
    long long idx4 = ((long long)blockIdx.x * blockDim.x + threadIdx.x) * 4;
    int row = (int)(idx4 / F);
    ushort4 o = make_ushort4(0, 0, 0, 0);
    if (row < Nn) {
        int c = (int)(idx4 & fmask);
        float4 v = *(const float4*)(x + idx4);
        float v0 = v.x * ss[c + 0] + ss[F + c + 0];
        float v1 = v.y * ss[c + 1] + ss[F + c + 1];
        float v2 = v.z * ss[c + 2] + ss[F + c + 2];
        float v3 = v.w * ss[c + 3] + ss[F + c + 3];
        v0 = (v0 > 0.f) ? v0 : (__expf(v0) - 1.f);
        v1 = (v1 > 0.f) ? v1 : (__expf(v1) - 1.f);
        v2 = (v2 > 0.f) ? v2 : (__expf(v2) - 1.f);
        v3 = (v3 > 0.f) ? v3 : (__expf(v3) - 1.f);
        o.x = f2bf(v0); o.y = f2bf(v1); o.z = f2bf(v2); o.w = f2bf(v3);
    }
    *(ushort4*)(outA + idx4) = o;
}

// log_softmax over 16 features per node
__global__ void log_softmax16(const float* __restrict__ x, float* __restrict__ out, int Nn) {
    int n = blockIdx.x * blockDim.x + threadIdx.x;
    if (n >= Nn) return;
    float v[16];
    float m = -1e30f;
#pragma unroll
    for (int i = 0; i < 16; ++i) { v[i] = x[n * 16 + i]; m = fmaxf(m, v[i]); }
    float s = 0.f;
#pragma unroll
    for (int i = 0; i < 16; ++i) s += __expf(v[i] - m);
    float l = __logf(s) + m;
#pragma unroll
    for (int i = 0; i < 16; ++i) out[n * 16 + i] = v[i] - l;
}

// ---------------------------------------------------------------------------
// Launcher
// ---------------------------------------------------------------------------
extern "C" void kernel_launch(void* const* d_in, const int* in_sizes, int n_in,
                              void* d_out, int out_size, void* d_ws, size_t ws_size,
                              hipStream_t stream) {
    const float* x   = (const float*)d_in[0];
    const int*   ei  = (const int*)d_in[1];
    const float* W1  = (const float*)d_in[2];
    const float* as1 = (const float*)d_in[3];
    const float* ad1 = (const float*)d_in[4];
    const float* b1  = (const float*)d_in[5];
    const float* ga1 = (const float*)d_in[6];
    const float* be1 = (const float*)d_in[7];
    const float* W2  = (const float*)d_in[8];
    const float* as2 = (const float*)d_in[9];
    const float* ad2 = (const float*)d_in[10];
    const float* b2  = (const float*)d_in[11];
    const float* ga2 = (const float*)d_in[12];
    const float* be2 = (const float*)d_in[13];
    const float* W3  = (const float*)d_in[14];
    const float* as3 = (const float*)d_in[15];
    const float* ad3 = (const float*)d_in[16];
    const float* b3  = (const float*)d_in[17];
    const float* ga3 = (const float*)d_in[18];
    const float* be3 = (const float*)d_in[19];
    const float* W4  = (const float*)d_in[20];
    const float* as4 = (const float*)d_in[21];
    const float* ad4 = (const float*)d_in[22];
    const float* b4  = (const float*)d_in[23];
    float* outp = (float*)d_out;

    uint8_t* base = (uint8_t*)d_ws;
    size_t off = 0;
    auto alloc = [&](size_t nbytes) -> void* {
        off = (off + 255) & ~(size_t)255;
        void* p = base + off;
        off += nbytes;
        return p;
    };
    float* bufO = (float*)alloc((size_t)NN * 512 * 4);                       // agg out (fp32, BN in)
    unsigned short* bufA = (unsigned short*)alloc((size_t)MPAD * 512 * 2);   // bf16 GEMM A
    unsigned short* hT   = (unsigned short*)alloc((size_t)8 * NN * 64 * 2);  // bf16 head-major h
    unsigned short* Wt1  = (unsigned short*)alloc((size_t)512 * 512 * 2);
    unsigned short* Wt2  = (unsigned short*)alloc((size_t)256 * 512 * 2);
    unsigned short* Wt3  = (unsigned short*)alloc((size_t)128 * 256 * 2);
    float* aSt  = (float*)alloc((size_t)8 * NN * 4);
    float* aDt  = (float*)alloc((size_t)8 * NN * 4);
    int*   cnt  = (int*)alloc((size_t)NN * 4);
    int*   rowp = (int*)alloc((size_t)(NN + 1) * 4);
    int*   wptr = (int*)alloc((size_t)NN * 4);
    int*   colx = (int*)alloc((size_t)ET * 4);
    float* bnp  = (float*)alloc((size_t)PCHUNK * 1024 * 4);  // BN partials
    float* bns  = (float*)alloc((size_t)1024 * 4);           // scale/shift

    const int* srcRow = ei;
    const int* dstRow = ei + EE;

    // ---- CSR build ----
    zero_i32<<<(NN + 255) / 256, 256, 0, stream>>>(cnt, NN);
    count_edges<<<(ET + 255) / 256, 256, 0, stream>>>(dstRow, cnt);
    scan20k<<<1, 1024, 0, stream>>>(cnt, rowp, wptr, NN);
    fill_edges<<<(ET + 255) / 256, 256, 0, stream>>>(srcRow, dstRow, wptr, colx);

    // ---- Weight transposes+casts (once) ----
    cvt_w_t<<<(512 * 512 + 255) / 256, 256, 0, stream>>>(W1, Wt1, 512, 512);
    cvt_w_t<<<(512 * 256 + 255) / 256, 256, 0, stream>>>(W2, Wt2, 512, 256);
    cvt_w_t<<<(256 * 128 + 255) / 256, 256, 0, stream>>>(W3, Wt3, 256, 128);

    // ---- Layer 1: Fin=512, H=8, C=64 (F=512) ----
    {
        cvt_a_bf16<<<((MPAD * 512 / 4) + 255) / 256, 256, 0, stream>>>(x, bufA, NN, MPAD, 512);
        dim3 g(512 / 128, MPAD / 128);
        gemm_bf16_fused<<<g, 256, 0, stream>>>(bufA, Wt1, hT, aSt, aDt, as1, ad1, NN, 512, 512, NN);
        gat_agg_bf<8, 64><<<8 * (NN / 4), 256, 0, stream>>>(hT, aSt, aDt, rowp, colx, b1, bufO, NN);
        bn_stats_part<<<dim3(512 / 128, PCHUNK), 128, 0, stream>>>(bufO, bnp, NN, 512);
        bn_finalize<<<1, 512, 0, stream>>>(bnp, ga1, be1, bns, 512, PCHUNK, 1.0f / NN);
        bn_apply_elu_bf16<<<(MPAD * 512 / 4) / 256, 256, 0, stream>>>(bufO, bns, bufA, NN, 512, 511);
    }
    // ---- Layer 2: Fin=512, H=4, C=64 (F=256) ----
    {
        dim3 g(256 / 128, MPAD / 128);
        gemm_bf16_fused<<<g, 256, 0, stream>>>(bufA, Wt2, hT, aSt, aDt, as2, ad2, NN, 256, 512, NN);
        gat_agg_bf<4, 64><<<4 * (NN / 4), 256, 0, stream>>>(hT, aSt, aDt, rowp, colx, b2, bufO, NN);
        bn_stats_part<<<dim3(256 / 128, PCHUNK), 128, 0, stream>>>(bufO, bnp, NN, 256);
        bn_finalize<<<1, 256, 0, stream>>>(bnp, ga2, be2, bns, 256, PCHUNK, 1.0f / NN);
        bn_apply_elu_bf16<<<(MPAD * 256 / 4) / 256, 256, 0, stream>>>(bufO, bns, bufA, NN, 256, 255);
    }
    // ---- Layer 3: Fin=256, H=2, C=64 (F=128) ----
    {
        dim3 g(128 / 128, MPAD / 128);
        gemm_bf16_fused<<<g, 256, 0, stream>>>(bufA, Wt3, hT, aSt, aDt, as3, ad3, NN, 128, 256, NN);
        gat_agg_bf<2, 64><<<2 * (NN / 4), 256, 0, stream>>>(hT, aSt, aDt, rowp, colx, b3, bufO, NN);
        bn_stats_part<<<dim3(128 / 128, PCHUNK), 128, 0, stream>>>(bufO, bnp, NN, 128);
        bn_finalize<<<1, 128, 0, stream>>>(bnp, ga3, be3, bns, 128, PCHUNK, 1.0f / NN);
        bn_apply_elu_bf16<<<(MPAD * 128 / 4) / 256, 256, 0, stream>>>(bufO, bns, bufA, NN, 128, 127);
    }
    // ---- Layer 4: Fin=128, H=1, C=16 (F=16) + log_softmax ----
    {
        // A for gemm_f32 must be fp32: bufO currently holds BN input (pre-activation).
        // Rebuild fp32 activations? No — bn_apply wrote bf16 bufA; use a bf16->f32-free
        // path: run fp32 GEMM on a float view reconstructed on the fly is costlier than
        // just using the bf16 activations with the fp32 GEMM reading converted values.
        // Simplest correct: small conversion of bufA (20000x128 bf16) into bufO (fp32).
        // 2.56M elems, ~1 us.
        // reuse log_softmax-style elementwise: do inline with cvt kernel below.
        {
            // convert bufA[0:NN,0:128] bf16 -> bufO fp32 (A for gemm_f32)
            struct L {};
            // simple lambda-free kernel launch:
        }
        // conversion kernel launch
        extern __global__ void bf2f_kernel(const unsigned short*, float*, long long);
        bf2f_kernel<<<((long long)NN * 128 / 4 + 255) / 256, 256, 0, stream>>>(bufA, bufO, (long long)NN * 128);
        dim3 g((16 + 63) / 64, (NN + 63) / 64);
        gemm_f32_bf16out<<<g, 256, 0, stream>>>(bufO, W4, hT, NN, 16, 128);
        att_scores_bf<16><<<(NN + 3) / 4, 256, 0, stream>>>(hT, as4, ad4, aSt, aDt, NN);
        gat_agg_bf<1, 16><<<1 * (NN / 4), 256, 0, stream>>>(hT, aSt, aDt, rowp, colx, b4, bufO, NN);
        log_softmax16<<<(NN + 255) / 256, 256, 0, stream>>>(bufO, outp, NN);
    }
}

// bf16 -> fp32 conversion, 4 elems/thread
__global__ void bf2f_kernel(const unsigned short* __restrict__ in, float* __restrict__ out,
                            long long n) {
    long long i = ((long long)blockIdx.x * blockDim.x + threadIdx.x) * 4;
    if (i >= n) return;
    ushort4 v = *(const ushort4*)(in + i);
    float4 o;
    o.x = bf2f(v.x); o.y = bf2f(v.y); o.z = bf2f(v.z); o.w = bf2f(v.w);
    *(float4*)(out + i) = o;
}

// Round 5
// 687.557 us; speedup vs baseline: 1.8418x; 1.0896x over previous
//
#include <hip/hip_runtime.h>
#include <hip/hip_bf16.h>
#include <cstdint>
#include <cstddef>

// Problem constants
#define NN 20000
#define EE 320000
#define ET (EE + NN)     // edges + self loops
#define MPAD 20096       // 157 * 128, M padded to tile
#define PCHUNK 79        // ceil(20000/256) row chunks for BN partials

typedef __attribute__((ext_vector_type(8))) short  short8;   // 8 bf16 (4 VGPRs)
typedef __attribute__((ext_vector_type(4))) float  floatx4;  // MFMA C/D frag

__device__ inline unsigned short f2bf(float f) {   // RNE fp32 -> bf16
    unsigned u = __float_as_uint(f);
    u += 0x7FFFu + ((u >> 16) & 1u);
    return (unsigned short)(u >> 16);
}
__device__ inline float bf2f(unsigned short b) {
    return __uint_as_float(((unsigned)b) << 16);
}
// packed bf16x2 in a uint -> two floats
__device__ inline float bflo(unsigned u) { return __uint_as_float(u << 16); }
__device__ inline float bfhi(unsigned u) { return __uint_as_float(u & 0xFFFF0000u); }

// ---------------------------------------------------------------------------
// Utility kernels
// ---------------------------------------------------------------------------
__global__ void zero_i32(int* __restrict__ p, int n) {
    int i = blockIdx.x * blockDim.x + threadIdx.x;
    if (i < n) p[i] = 0;
}

__global__ void bf2f_kernel(const unsigned short* __restrict__ in, float* __restrict__ out,
                            long long n) {
    long long i = ((long long)blockIdx.x * blockDim.x + threadIdx.x) * 4;
    if (i >= n) return;
    ushort4 v = *(const ushort4*)(in + i);
    float4 o;
    o.x = bf2f(v.x); o.y = bf2f(v.y); o.z = bf2f(v.z); o.w = bf2f(v.w);
    *(float4*)(out + i) = o;
}

// fp32 [M,K] -> bf16 [Mpad,K], rows >= M zero-filled. 4 elems/thread.
__global__ void cvt_a_bf16(const float* __restrict__ in, unsigned short* __restrict__ out,
                           int M, int Mpad, int K) {
    long long base = ((long long)blockIdx.x * blockDim.x + threadIdx.x) * 4;
    if (base >= (long long)Mpad * K) return;
    int row = (int)(base / K);
    float4 v = make_float4(0.f, 0.f, 0.f, 0.f);
    if (row < M) v = *(const float4*)(in + base);
    ushort4 o;
    o.x = f2bf(v.x); o.y = f2bf(v.y); o.z = f2bf(v.z); o.w = f2bf(v.w);
    *(ushort4*)(out + base) = o;
}

// W [K,N] fp32 -> Wt [N,K] bf16 (once per launch; small)
__global__ void cvt_w_t(const float* __restrict__ W, unsigned short* __restrict__ Wt,
                        int K, int N) {
    int i = blockIdx.x * blockDim.x + threadIdx.x;
    if (i >= K * N) return;
    int k = i / N, n = i - k * N;
    Wt[(size_t)n * K + k] = f2bf(W[i]);
}

// ---------------------------------------------------------------------------
// CSR build: count -> scan -> fill   (dst-major CSR, built once per launch)
// ---------------------------------------------------------------------------
__global__ void count_edges(const int* __restrict__ dst, int* __restrict__ cnt) {
    int e = blockIdx.x * blockDim.x + threadIdx.x;
    if (e >= ET) return;
    int d = (e < EE) ? dst[e] : (e - EE);
    atomicAdd(&cnt[d], 1);
}

__global__ void scan20k(const int* __restrict__ cnt, int* __restrict__ rowp,
                        int* __restrict__ wptr, int n) {
    __shared__ int sd[1024];
    __shared__ int run;
    int t = threadIdx.x;
    if (t == 0) run = 0;
    __syncthreads();
    for (int base = 0; base < n; base += 1024) {
        int i = base + t;
        int v = (i < n) ? cnt[i] : 0;
        sd[t] = v;
        __syncthreads();
        for (int o = 1; o < 1024; o <<= 1) {
            int u = (t >= o) ? sd[t - o] : 0;
            __syncthreads();
            sd[t] += u;
            __syncthreads();
        }
        int incl = sd[t];
        int excl = incl - v;
        if (i < n) { int rp = run + excl; rowp[i] = rp; wptr[i] = rp; }
        __syncthreads();
        if (t == 1023) run += sd[1023];
        __syncthreads();
    }
    if (t == 0) rowp[n] = run;
}

__global__ void fill_edges(const int* __restrict__ src, const int* __restrict__ dst,
                           int* __restrict__ wptr, int* __restrict__ colx) {
    int e = blockIdx.x * blockDim.x + threadIdx.x;
    if (e >= ET) return;
    int s, d;
    if (e < EE) { s = src[e]; d = dst[e]; } else { s = e - EE; d = e - EE; }
    int pos = atomicAdd(&wptr[d], 1);
    colx[pos] = s;
}

// ---------------------------------------------------------------------------
// BF16 MFMA GEMM with fused epilogue (node-major outputs):
//   - hN[row][col] bf16  (node-major h, col = head*64 + c)
//   - aS[row][head], aD[row][head] fp32 (attention dots), H = N/64
// C[M,N] = A[Mpad,K] * Bt[N,K]^T. 128x128 tile, 4 waves, 16x16x32 MFMA.
// ---------------------------------------------------------------------------
__global__ __launch_bounds__(256) void gemm_bf16_fused(
        const unsigned short* __restrict__ A, const unsigned short* __restrict__ Bt,
        unsigned short* __restrict__ hN, float* __restrict__ aS, float* __restrict__ aD,
        const float* __restrict__ atts, const float* __restrict__ attd,
        int M, int N, int K) {
    __shared__ unsigned short As[128][40];
    __shared__ unsigned short Bs[128][40];
    const int t = threadIdx.x;
    const int lane = t & 63, wave = t >> 6;
    const int wm = wave >> 1, wn = wave & 1;
    const int quad = lane >> 4, mrow = lane & 15;
    const int row0 = blockIdx.y * 128, col0 = blockIdx.x * 128;
    const int srow = t >> 2, schunk = (t & 3) * 8;
    const int H = N >> 6;

    floatx4 acc[4][4];
#pragma unroll
    for (int i = 0; i < 4; ++i)
#pragma unroll
        for (int j = 0; j < 4; ++j)
#pragma unroll
            for (int r = 0; r < 4; ++r) acc[i][j][r] = 0.f;

    for (int k0 = 0; k0 < K; k0 += 32) {
        uint4 ra0 = *(const uint4*)(A  + (size_t)(row0 + srow)      * K + k0 + schunk);
        uint4 ra1 = *(const uint4*)(A  + (size_t)(row0 + srow + 64) * K + k0 + schunk);
        uint4 rb0 = *(const uint4*)(Bt + (size_t)(col0 + srow)      * K + k0 + schunk);
        uint4 rb1 = *(const uint4*)(Bt + (size_t)(col0 + srow + 64) * K + k0 + schunk);
        __syncthreads();
        *(uint4*)&As[srow][schunk]      = ra0;
        *(uint4*)&As[srow + 64][schunk] = ra1;
        *(uint4*)&Bs[srow][schunk]      = rb0;
        *(uint4*)&Bs[srow + 64][schunk] = rb1;
        __syncthreads();

        short8 af[4], bfr[4];
#pragma unroll
        for (int i = 0; i < 4; ++i)
            af[i] = *(const short8*)&As[wm * 64 + i * 16 + mrow][quad * 8];
#pragma unroll
        for (int j = 0; j < 4; ++j)
            bfr[j] = *(const short8*)&Bs[wn * 64 + j * 16 + mrow][quad * 8];
#pragma unroll
        for (int i = 0; i < 4; ++i)
#pragma unroll
            for (int j = 0; j < 4; ++j)
                acc[i][j] = __builtin_amdgcn_mfma_f32_16x16x32_bf16(af[i], bfr[j], acc[i][j], 0, 0, 0);
    }

    // ---- fused epilogue ----
    const int head = (col0 + wn * 64) >> 6;
    float attS[4], attD[4];
#pragma unroll
    for (int j = 0; j < 4; ++j) {
        attS[j] = atts[head * 64 + j * 16 + mrow];
        attD[j] = attd[head * 64 + j * 16 + mrow];
    }

#pragma unroll
    for (int i = 0; i < 4; ++i) {
#pragma unroll
        for (int r = 0; r < 4; ++r) {
            int row = row0 + wm * 64 + i * 16 + quad * 4 + r;
            float ps = acc[i][0][r] * attS[0] + acc[i][1][r] * attS[1]
                     + acc[i][2][r] * attS[2] + acc[i][3][r] * attS[3];
            float pd = acc[i][0][r] * attD[0] + acc[i][1][r] * attD[1]
                     + acc[i][2][r] * attD[2] + acc[i][3][r] * attD[3];
#pragma unroll
            for (int o = 1; o < 16; o <<= 1) {
                ps += __shfl_xor(ps, o);
                pd += __shfl_xor(pd, o);
            }
            if (row < M) {
                if (mrow == 0) {
                    aS[(size_t)row * H + head] = ps;
                    aD[(size_t)row * H + head] = pd;
                }
#pragma unroll
                for (int j = 0; j < 4; ++j)
                    hN[(size_t)row * N + col0 + wn * 64 + j * 16 + mrow] = f2bf(acc[i][j][r]);
            }
        }
    }
}

// ---------------------------------------------------------------------------
// GAT aggregation, all heads per wave. One wave per dst node, 4 waves/block.
// hN node-major bf16 [Nn][F], F = H*64. aS/aD node-major [Nn][H].
// Lane l covers flat channels [l*H, l*H+H) (one head: head = l*H/64).
// Pass 1: per-head online softmax (m,s) with lanes=edges + butterflies.
// Pass 2: recompute p, park (src, p[H]) in per-wave LDS, then lanes=channels
// gather hN rows coalesced (2H B/lane) 4-deep unrolled.
// ---------------------------------------------------------------------------
template <int H>
__global__ __launch_bounds__(256) void gat_agg_all(
        const unsigned short* __restrict__ hN,
        const float* __restrict__ aS, const float* __restrict__ aD,
        const int* __restrict__ rowp, const int* __restrict__ colx,
        const float* __restrict__ bias, float* __restrict__ out, int Nn) {
    constexpr int F = H * 64;
    __shared__ float pbuf[4][64 * H];
    __shared__ int   snbuf[4][64];
    const int wave = threadIdx.x >> 6, lane = threadIdx.x & 63;
    const int n = blockIdx.x * 4 + wave;
    if (n >= Nn) return;
    const int hd = (lane * H) >> 6;       // this lane's head
    const int chbase = lane * H;          // flat channel base

    const int b0 = rowp[n], b1 = rowp[n + 1];

    float adv[H];
#pragma unroll
    for (int h = 0; h < H; ++h) adv[h] = aD[(size_t)n * H + h];   // broadcast

    // ---- pass 1: per-head m, s ----
    float m[H], s[H];
#pragma unroll
    for (int h = 0; h < H; ++h) { m[h] = -1e30f; s[h] = 0.f; }
    for (int c0 = b0; c0 < b1; c0 += 64) {
        int cnt = min(64, b1 - c0);
        float e[H];
#pragma unroll
        for (int h = 0; h < H; ++h) e[h] = -1e30f;
        if (lane < cnt) {
            int sn = colx[c0 + lane];
#pragma unroll
            for (int h = 0; h < H; ++h) {
                float tt = aS[(size_t)sn * H + h] + adv[h];
                e[h] = (tt > 0.f) ? tt : 0.2f * tt;
            }
        }
#pragma unroll
        for (int h = 0; h < H; ++h) {
            float mc = e[h];
#pragma unroll
            for (int o = 32; o > 0; o >>= 1) mc = fmaxf(mc, __shfl_xor(mc, o));
            float nm = fmaxf(m[h], mc);
            s[h] *= __expf(m[h] - nm);
            float p = (lane < cnt) ? __expf(e[h] - nm) : 0.f;
#pragma unroll
            for (int o = 32; o > 0; o >>= 1) p += __shfl_xor(p, o);
            s[h] += p; m[h] = nm;
        }
    }
    float inv[H];
#pragma unroll
    for (int h = 0; h < H; ++h) inv[h] = 1.f / s[h];

    // ---- pass 2: probs -> LDS, coalesced gather ----
    float acc[H];
#pragma unroll
    for (int h = 0; h < H; ++h) acc[h] = 0.f;

    for (int c0 = b0; c0 < b1; c0 += 64) {
        int cnt = min(64, b1 - c0);
        if (lane < cnt) {
            int sn = colx[c0 + lane];
            snbuf[wave][lane] = sn;
#pragma unroll
            for (int h = 0; h < H; ++h) {
                float tt = aS[(size_t)sn * H + h] + adv[h];
                tt = (tt > 0.f) ? tt : 0.2f * tt;
                pbuf[wave][lane * H + h] = __expf(tt - m[h]) * inv[h];
            }
        }
        __threadfence_block();   // LDS writes visible before reads (intra-wave)

        int j = 0;
        for (; j + 4 <= cnt; j += 4) {
            int s0 = snbuf[wave][j],     s1 = snbuf[wave][j + 1];
            int s2 = snbuf[wave][j + 2], s3 = snbuf[wave][j + 3];
            float p0 = pbuf[wave][(j + 0) * H + hd];
            float p1 = pbuf[wave][(j + 1) * H + hd];
            float p2 = pbuf[wave][(j + 2) * H + hd];
            float p3 = pbuf[wave][(j + 3) * H + hd];
            const unsigned* r0 = (const unsigned*)(hN + (size_t)s0 * F + chbase);
            const unsigned* r1 = (const unsigned*)(hN + (size_t)s1 * F + chbase);
            const unsigned* r2 = (const unsigned*)(hN + (size_t)s2 * F + chbase);
            const unsigned* r3 = (const unsigned*)(hN + (size_t)s3 * F + chbase);
#pragma unroll
            for (int k = 0; k < H / 2; ++k) {
                unsigned u0 = r0[k], u1 = r1[k], u2 = r2[k], u3 = r3[k];
                acc[2 * k]     += p0 * bflo(u0) + p1 * bflo(u1) + p2 * bflo(u2) + p3 * bflo(u3);
                acc[2 * k + 1] += p0 * bfhi(u0) + p1 * bfhi(u1) + p2 * bfhi(u2) + p3 * bfhi(u3);
            }
        }
        for (; j < cnt; ++j) {
            int sj = snbuf[wave][j];
            float pj = pbuf[wave][j * H + hd];
            const unsigned* rr = (const unsigned*)(hN + (size_t)sj * F + chbase);
#pragma unroll
            for (int k = 0; k < H / 2; ++k) {
                unsigned u = rr[k];
                acc[2 * k]     += pj * bflo(u);
                acc[2 * k + 1] += pj * bfhi(u);
            }
        }
        __threadfence_block();   // reads done before next chunk overwrites
    }

#pragma unroll
    for (int h = 0; h < H; ++h)
        out[(size_t)n * F + chbase + h] = acc[h] + bias[chbase + h];
}

// ---------------------------------------------------------------------------
// FP32 tiled GEMM for layer 4 (N=16) -> writes bf16 hN (single head, C=16)
// ---------------------------------------------------------------------------
__global__ __launch_bounds__(256) void gemm_f32_bf16out(const float* __restrict__ A,
                                                        const float* __restrict__ B,
                                                        unsigned short* __restrict__ C,
                                                        int M, int N, int K) {
    __shared__ float As[16][65];
    __shared__ float Bs[16][64];
    const int tid = threadIdx.x;
    const int tx = tid & 15, ty = tid >> 4;
    const int row0 = blockIdx.y * 64, col0 = blockIdx.x * 64;
    const int rA = tid >> 2, kq = (tid & 3) << 2;
    const int rB = tid >> 4, cq = (tid & 15) << 2;
    float acc[4][4] = {};

    for (int k0 = 0; k0 < K; k0 += 16) {
        float4 fa = make_float4(0.f, 0.f, 0.f, 0.f);
        int arow = row0 + rA;
        if (arow < M) fa = *(const float4*)(A + (size_t)arow * K + k0 + kq);
        float4 fb = make_float4(0.f, 0.f, 0.f, 0.f);
        int bcol = col0 + cq;
        if (bcol < N) fb = *(const float4*)(B + (size_t)(k0 + rB) * N + bcol);
        As[kq + 0][rA] = fa.x; As[kq + 1][rA] = fa.y;
        As[kq + 2][rA] = fa.z; As[kq + 3][rA] = fa.w;
        *(float4*)&Bs[rB][cq] = fb;
        __syncthreads();
#pragma unroll
        for (int k = 0; k < 16; ++k) {
            float a0 = As[k][ty * 4 + 0];
            float a1 = As[k][ty * 4 + 1];
            float a2 = As[k][ty * 4 + 2];
            float a3 = As[k][ty * 4 + 3];
            float4 b = *(float4*)&Bs[k][tx * 4];
            acc[0][0] += a0 * b.x; acc[0][1] += a0 * b.y; acc[0][2] += a0 * b.z; acc[0][3] += a0 * b.w;
            acc[1][0] += a1 * b.x; acc[1][1] += a1 * b.y; acc[1][2] += a1 * b.z; acc[1][3] += a1 * b.w;
            acc[2][0] += a2 * b.x; acc[2][1] += a2 * b.y; acc[2][2] += a2 * b.z; acc[2][3] += a2 * b.w;
            acc[3][0] += a3 * b.x; acc[3][1] += a3 * b.y; acc[3][2] += a3 * b.z; acc[3][3] += a3 * b.w;
        }
        __syncthreads();
    }
#pragma unroll
    for (int i = 0; i < 4; ++i) {
        int r = row0 + ty * 4 + i;
        if (r >= M) continue;
#pragma unroll
        for (int jj = 0; jj < 4; ++jj) {
            int c = col0 + tx * 4 + jj;
            if (c < N) C[(size_t)r * N + c] = f2bf(acc[i][jj]);
        }
    }
}

// ---------------------------------------------------------------------------
// Attention scores from bf16 h (layer 4 only): one wave per node, H=1.
// ---------------------------------------------------------------------------
template <int C>
__global__ void att_scores_bf(const unsigned short* __restrict__ h,
                              const float* __restrict__ atts, const float* __restrict__ attd,
                              float* __restrict__ aS, float* __restrict__ aD, int Nn) {
    int wid = (blockIdx.x * blockDim.x + threadIdx.x) >> 6;
    int lane = threadIdx.x & 63;
    if (wid >= Nn) return;
    float sv = 0.f, dv = 0.f;
    if (lane < C) {
        float v = bf2f(h[(size_t)wid * C + lane]);
        sv = v * atts[lane];
        dv = v * attd[lane];
    }
#pragma unroll
    for (int o = 32; o > 0; o >>= 1) {
        sv += __shfl_down(sv, o);
        dv += __shfl_down(dv, o);
    }
    if (lane == 0) { aS[wid] = sv; aD[wid] = dv; }
}

// ---------------------------------------------------------------------------
// GAT aggregation for layer 4 (H=1, C=16): per-(dst)-wave flash-style.
// ---------------------------------------------------------------------------
template <int H, int C>
__global__ void gat_agg_bf(const unsigned short* __restrict__ hT,
                           const float* __restrict__ aSt, const float* __restrict__ aDt,
                           const int* __restrict__ rowp, const int* __restrict__ colx,
                           const float* __restrict__ bias, float* __restrict__ out, int Nn) {
    int b = blockIdx.x;
    int head = b % H;
    int n = (b / H) * 4 + (threadIdx.x >> 6);
    int lane = threadIdx.x & 63;
    if (n >= Nn) return;
    const unsigned short* ht = hT + (size_t)head * Nn * C;
    const float* as = aSt + (size_t)head * Nn;
    float adv = aDt[(size_t)head * Nn + n];
    int b0 = rowp[n], b1 = rowp[n + 1];

    float m = -1e30f, s = 0.f, acc = 0.f;
    for (int c0 = b0; c0 < b1; c0 += 64) {
        int cnt = b1 - c0; if (cnt > 64) cnt = 64;
        int sn = 0; float e = -1e30f;
        if (lane < cnt) {
            sn = colx[c0 + lane];
            float tt = as[sn] + adv;
            e = (tt > 0.f) ? tt : 0.2f * tt;
        }
        float mc = e;
#pragma unroll
        for (int o = 32; o > 0; o >>= 1) mc = fmaxf(mc, __shfl_xor(mc, o));
        float nm = fmaxf(m, mc);
        float sc = __expf(m - nm);
        acc *= sc; s *= sc;
        float p = (lane < cnt) ? __expf(e - nm) : 0.f;
        float ps = p;
#pragma unroll
        for (int o = 32; o > 0; o >>= 1) ps += __shfl_xor(ps, o);
        s += ps; m = nm;

        int j = 0;
        for (; j + 4 <= cnt; j += 4) {
            int s0 = __shfl(sn, j),     s1 = __shfl(sn, j + 1);
            int s2 = __shfl(sn, j + 2), s3 = __shfl(sn, j + 3);
            float p0 = __shfl(p, j),     p1 = __shfl(p, j + 1);
            float p2 = __shfl(p, j + 2), p3 = __shfl(p, j + 3);
            float h0 = 0.f, h1 = 0.f, h2 = 0.f, h3 = 0.f;
            if (lane < C) {
                h0 = bf2f(ht[(size_t)s0 * C + lane]);
                h1 = bf2f(ht[(size_t)s1 * C + lane]);
                h2 = bf2f(ht[(size_t)s2 * C + lane]);
                h3 = bf2f(ht[(size_t)s3 * C + lane]);
            }
            acc += p0 * h0 + p1 * h1 + p2 * h2 + p3 * h3;
        }
        for (; j < cnt; ++j) {
            int sj = __shfl(sn, j);
            float pj = __shfl(p, j);
            float hv = (lane < C) ? bf2f(ht[(size_t)sj * C + lane]) : 0.f;
            acc += pj * hv;
        }
    }
    if (lane < C)
        out[(size_t)n * (H * C) + head * C + lane] = acc / s + bias[head * C + lane];
}

// ---------------------------------------------------------------------------
// BatchNorm: partial stats -> finalize -> apply+ELU writing bf16 A buffer.
// ---------------------------------------------------------------------------
__global__ void bn_stats_part(const float* __restrict__ x, float* __restrict__ part,
                              int Nn, int F) {
    int col = blockIdx.x * blockDim.x + threadIdx.x;
    int r0 = blockIdx.y * 256;
    int r1 = min(r0 + 256, Nn);
    float s = 0.f, q = 0.f;
    for (int r = r0; r < r1; ++r) {
        float v = x[(size_t)r * F + col];
        s += v; q += v * v;
    }
    part[(size_t)blockIdx.y * 2 * F + col] = s;
    part[(size_t)blockIdx.y * 2 * F + F + col] = q;
}

__global__ void bn_finalize(const float* __restrict__ part, const float* __restrict__ gamma,
                            const float* __restrict__ beta, float* __restrict__ ss,
                            int F, int P, float invN) {
    int c = threadIdx.x;
    if (c >= F) return;
    float s = 0.f, q = 0.f;
    for (int p = 0; p < P; ++p) {
        s += part[(size_t)p * 2 * F + c];
        q += part[(size_t)p * 2 * F + F + c];
    }
    float mu = s * invN;
    float var = q * invN - mu * mu;
    float sc = gamma[c] * rsqrtf(var + 1e-5f);
    ss[c] = sc;
    ss[F + c] = beta[c] - mu * sc;
}

__global__ void bn_apply_elu_bf16(const float* __restrict__ x, const float* __restrict__ ss,
                                  unsigned short* __restrict__ outA,
                                  int Nn, int F, int fmask) {
    long long idx4 = ((long long)blockIdx.x * blockDim.x + threadIdx.x) * 4;
    int row = (int)(idx4 / F);
    ushort4 o = make_ushort4(0, 0, 0, 0);
    if (row < Nn) {
        int c = (int)(idx4 & fmask);
        float4 v = *(const float4*)(x + idx4);
        float v0 = v.x * ss[c + 0] + ss[F + c + 0];
        float v1 = v.y * ss[c + 1] + ss[F + c + 1];
        float v2 = v.z * ss[c + 2] + ss[F + c + 2];
        float v3 = v.w * ss[c + 3] + ss[F + c + 3];
        v0 = (v0 > 0.f) ? v0 : (__expf(v0) - 1.f);
        v1 = (v1 > 0.f) ? v1 : (__expf(v1) - 1.f);
        v2 = (v2 > 0.f) ? v2 : (__expf(v2) - 1.f);
        v3 = (v3 > 0.f) ? v3 : (__expf(v3) - 1.f);
        o.x = f2bf(v0); o.y = f2bf(v1); o.z = f2bf(v2); o.w = f2bf(v3);
    }
    *(ushort4*)(outA + idx4) = o;
}

// log_softmax over 16 features per node
__global__ void log_softmax16(const float* __restrict__ x, float* __restrict__ out, int Nn) {
    int n = blockIdx.x * blockDim.x + threadIdx.x;
    if (n >= Nn) return;
    float v[16];
    float m = -1e30f;
#pragma unroll
    for (int i = 0; i < 16; ++i) { v[i] = x[n * 16 + i]; m = fmaxf(m, v[i]); }
    float s = 0.f;
#pragma unroll
    for (int i = 0; i < 16; ++i) s += __expf(v[i] - m);
    float l = __logf(s) + m;
#pragma unroll
    for (int i = 0; i < 16; ++i) out[n * 16 + i] = v[i] - l;
}

// ---------------------------------------------------------------------------
// Launcher
// ---------------------------------------------------------------------------
extern "C" void kernel_launch(void* const* d_in, const int* in_sizes, int n_in,
                              void* d_out, int out_size, void* d_ws, size_t ws_size,
                              hipStream_t stream) {
    const float* x   = (const float*)d_in[0];
    const int*   ei  = (const int*)d_in[1];
    const float* W1  = (const float*)d_in[2];
    const float* as1 = (const float*)d_in[3];
    const float* ad1 = (const float*)d_in[4];
    const float* b1  = (const float*)d_in[5];
    const float* ga1 = (const float*)d_in[6];
    const float* be1 = (const float*)d_in[7];
    const float* W2  = (const float*)d_in[8];
    const float* as2 = (const float*)d_in[9];
    const float* ad2 = (const float*)d_in[10];
    const float* b2  = (const float*)d_in[11];
    const float* ga2 = (const float*)d_in[12];
    const float* be2 = (const float*)d_in[13];
    const float* W3  = (const float*)d_in[14];
    const float* as3 = (const float*)d_in[15];
    const float* ad3 = (const float*)d_in[16];
    const float* b3  = (const float*)d_in[17];
    const float* ga3 = (const float*)d_in[18];
    const float* be3 = (const float*)d_in[19];
    const float* W4  = (const float*)d_in[20];
    const float* as4 = (const float*)d_in[21];
    const float* ad4 = (const float*)d_in[22];
    const float* b4  = (const float*)d_in[23];
    float* outp = (float*)d_out;

    uint8_t* base = (uint8_t*)d_ws;
    size_t off = 0;
    auto alloc = [&](size_t nbytes) -> void* {
        off = (off + 255) & ~(size_t)255;
        void* p = base + off;
        off += nbytes;
        return p;
    };
    float* bufO = (float*)alloc((size_t)NN * 512 * 4);                       // agg out (fp32, BN in)
    unsigned short* bufA = (unsigned short*)alloc((size_t)MPAD * 512 * 2);   // bf16 GEMM A
    unsigned short* hN   = (unsigned short*)alloc((size_t)NN * 512 * 2);     // bf16 node-major h
    unsigned short* Wt1  = (unsigned short*)alloc((size_t)512 * 512 * 2);
    unsigned short* Wt2  = (unsigned short*)alloc((size_t)256 * 512 * 2);
    unsigned short* Wt3  = (unsigned short*)alloc((size_t)128 * 256 * 2);
    float* aSn  = (float*)alloc((size_t)NN * 8 * 4);
    float* aDn  = (float*)alloc((size_t)NN * 8 * 4);
    int*   cnt  = (int*)alloc((size_t)NN * 4);
    int*   rowp = (int*)alloc((size_t)(NN + 1) * 4);
    int*   wptr = (int*)alloc((size_t)NN * 4);
    int*   colx = (int*)alloc((size_t)ET * 4);
    float* bnp  = (float*)alloc((size_t)PCHUNK * 1024 * 4);  // BN partials
    float* bns  = (float*)alloc((size_t)1024 * 4);           // scale/shift

    const int* srcRow = ei;
    const int* dstRow = ei + EE;

    // ---- CSR build ----
    zero_i32<<<(NN + 255) / 256, 256, 0, stream>>>(cnt, NN);
    count_edges<<<(ET + 255) / 256, 256, 0, stream>>>(dstRow, cnt);
    scan20k<<<1, 1024, 0, stream>>>(cnt, rowp, wptr, NN);
    fill_edges<<<(ET + 255) / 256, 256, 0, stream>>>(srcRow, dstRow, wptr, colx);

    // ---- Weight transposes+casts (once) ----
    cvt_w_t<<<(512 * 512 + 255) / 256, 256, 0, stream>>>(W1, Wt1, 512, 512);
    cvt_w_t<<<(512 * 256 + 255) / 256, 256, 0, stream>>>(W2, Wt2, 512, 256);
    cvt_w_t<<<(256 * 128 + 255) / 256, 256, 0, stream>>>(W3, Wt3, 256, 128);

    // ---- Layer 1: Fin=512, H=8, C=64 (F=512) ----
    {
        cvt_a_bf16<<<((MPAD * 512 / 4) + 255) / 256, 256, 0, stream>>>(x, bufA, NN, MPAD, 512);
        dim3 g(512 / 128, MPAD / 128);
        gemm_bf16_fused<<<g, 256, 0, stream>>>(bufA, Wt1, hN, aSn, aDn, as1, ad1, NN, 512, 512);
        gat_agg_all<8><<<NN / 4, 256, 0, stream>>>(hN, aSn, aDn, rowp, colx, b1, bufO, NN);
        bn_stats_part<<<dim3(512 / 128, PCHUNK), 128, 0, stream>>>(bufO, bnp, NN, 512);
        bn_finalize<<<1, 512, 0, stream>>>(bnp, ga1, be1, bns, 512, PCHUNK, 1.0f / NN);
        bn_apply_elu_bf16<<<(MPAD * 512 / 4) / 256, 256, 0, stream>>>(bufO, bns, bufA, NN, 512, 511);
    }
    // ---- Layer 2: Fin=512, H=4, C=64 (F=256) ----
    {
        dim3 g(256 / 128, MPAD / 128);
        gemm_bf16_fused<<<g, 256, 0, stream>>>(bufA, Wt2, hN, aSn, aDn, as2, ad2, NN, 256, 512);
        gat_agg_all<4><<<NN / 4, 256, 0, stream>>>(hN, aSn, aDn, rowp, colx, b2, bufO, NN);
        bn_stats_part<<<dim3(256 / 128, PCHUNK), 128, 0, stream>>>(bufO, bnp, NN, 256);
        bn_finalize<<<1, 256, 0, stream>>>(bnp, ga2, be2, bns, 256, PCHUNK, 1.0f / NN);
        bn_apply_elu_bf16<<<(MPAD * 256 / 4) / 256, 256, 0, stream>>>(bufO, bns, bufA, NN, 256, 255);
    }
    // ---- Layer 3: Fin=256, H=2, C=64 (F=128) ----
    {
        dim3 g(128 / 128, MPAD / 128);
        gemm_bf16_fused<<<g, 256, 0, stream>>>(bufA, Wt3, hN, aSn, aDn, as3, ad3, NN, 128, 256);
        gat_agg_all<2><<<NN / 4, 256, 0, stream>>>(hN, aSn, aDn, rowp, colx, b3, bufO, NN);
        bn_stats_part<<<dim3(128 / 128, PCHUNK), 128, 0, stream>>>(bufO, bnp, NN, 128);
        bn_finalize<<<1, 128, 0, stream>>>(bnp, ga3, be3, bns, 128, PCHUNK, 1.0f / NN);
        bn_apply_elu_bf16<<<(MPAD * 128 / 4) / 256, 256, 0, stream>>>(bufO, bns, bufA, NN, 128, 127);
    }
    // ---- Layer 4: Fin=128, H=1, C=16 (F=16) + log_softmax ----
    {
        bf2f_kernel<<<(int)(((long long)NN * 128 / 4 + 255) / 256), 256, 0, stream>>>(
            bufA, bufO, (long long)NN * 128);
        dim3 g((16 + 63) / 64, (NN + 63) / 64);
        gemm_f32_bf16out<<<g, 256, 0, stream>>>(bufO, W4, hN, NN, 16, 128);
        att_scores_bf<16><<<(NN + 3) / 4, 256, 0, stream>>>(hN, as4, ad4, aSn, aDn, NN);
        gat_agg_bf<1, 16><<<NN / 4, 256, 0, stream>>>(hN, aSn, aDn, rowp, colx, b4, bufO, NN);
        log_softmax16<<<(NN + 255) / 256, 256, 0, stream>>>(bufO, outp, NN);
    }
}

// Round 7
// 650.922 us; speedup vs baseline: 1.9455x; 1.0563x over previous
//
#include <hip/hip_runtime.h>
#include <hip/hip_bf16.h>
#include <cstdint>
#include <cstddef>

// Problem constants
#define NN 20000
#define EE 320000
#define ET (EE + NN)     // edges + self loops
#define MPAD 20096       // 157 * 128, M padded to tile
#define BNP 256          // BN stage-1 partial blocks (deterministic)

typedef __attribute__((ext_vector_type(8))) short  short8;   // 8 bf16 (4 VGPRs)
typedef __attribute__((ext_vector_type(4))) float  floatx4;  // MFMA C/D frag

__device__ inline unsigned short f2bf(float f) {   // RNE fp32 -> bf16
    unsigned u = __float_as_uint(f);
    u += 0x7FFFu + ((u >> 16) & 1u);
    return (unsigned short)(u >> 16);
}
__device__ inline float bf2f(unsigned short b) {
    return __uint_as_float(((unsigned)b) << 16);
}
// packed bf16x2 in a uint -> two floats
__device__ inline float bflo(unsigned u) { return __uint_as_float(u << 16); }
__device__ inline float bfhi(unsigned u) { return __uint_as_float(u & 0xFFFF0000u); }

// ---------------------------------------------------------------------------
// Utility kernels
// ---------------------------------------------------------------------------
__global__ void zero_i32(int* __restrict__ p, int n) {
    int i = blockIdx.x * blockDim.x + threadIdx.x;
    if (i < n) p[i] = 0;
}

__global__ void bf2f_kernel(const unsigned short* __restrict__ in, float* __restrict__ out,
                            long long n) {
    long long i = ((long long)blockIdx.x * blockDim.x + threadIdx.x) * 4;
    if (i >= n) return;
    ushort4 v = *(const ushort4*)(in + i);
    float4 o;
    o.x = bf2f(v.x); o.y = bf2f(v.y); o.z = bf2f(v.z); o.w = bf2f(v.w);
    *(float4*)(out + i) = o;
}

// fp32 [M,K] -> bf16 [Mpad,K], rows >= M zero-filled. 4 elems/thread.
__global__ void cvt_a_bf16(const float* __restrict__ in, unsigned short* __restrict__ out,
                           int M, int Mpad, int K) {
    long long base = ((long long)blockIdx.x * blockDim.x + threadIdx.x) * 4;
    if (base >= (long long)Mpad * K) return;
    int row = (int)(base / K);
    float4 v = make_float4(0.f, 0.f, 0.f, 0.f);
    if (row < M) v = *(const float4*)(in + base);
    ushort4 o;
    o.x = f2bf(v.x); o.y = f2bf(v.y); o.z = f2bf(v.z); o.w = f2bf(v.w);
    *(ushort4*)(out + base) = o;
}

// W [K,N] fp32 -> Wt [N,K] bf16 (once per launch; small)
__global__ void cvt_w_t(const float* __restrict__ W, unsigned short* __restrict__ Wt,
                        int K, int N) {
    int i = blockIdx.x * blockDim.x + threadIdx.x;
    if (i >= K * N) return;
    int k = i / N, n = i - k * N;
    Wt[(size_t)n * K + k] = f2bf(W[i]);
}

// ---------------------------------------------------------------------------
// CSR build: count -> scan -> fill   (dst-major CSR, built once per launch)
// ---------------------------------------------------------------------------
__global__ void count_edges(const int* __restrict__ dst, int* __restrict__ cnt) {
    int e = blockIdx.x * blockDim.x + threadIdx.x;
    if (e >= ET) return;
    int d = (e < EE) ? dst[e] : (e - EE);
    atomicAdd(&cnt[d], 1);
}

__global__ void scan20k(const int* __restrict__ cnt, int* __restrict__ rowp,
                        int* __restrict__ wptr, int n) {
    __shared__ int sd[1024];
    __shared__ int run;
    int t = threadIdx.x;
    if (t == 0) run = 0;
    __syncthreads();
    for (int base = 0; base < n; base += 1024) {
        int i = base + t;
        int v = (i < n) ? cnt[i] : 0;
        sd[t] = v;
        __syncthreads();
        for (int o = 1; o < 1024; o <<= 1) {
            int u = (t >= o) ? sd[t - o] : 0;
            __syncthreads();
            sd[t] += u;
            __syncthreads();
        }
        int incl = sd[t];
        int excl = incl - v;
        if (i < n) { int rp = run + excl; rowp[i] = rp; wptr[i] = rp; }
        __syncthreads();
        if (t == 1023) run += sd[1023];
        __syncthreads();
    }
    if (t == 0) rowp[n] = run;
}

__global__ void fill_edges(const int* __restrict__ src, const int* __restrict__ dst,
                           int* __restrict__ wptr, int* __restrict__ colx) {
    int e = blockIdx.x * blockDim.x + threadIdx.x;
    if (e >= ET) return;
    int s, d;
    if (e < EE) { s = src[e]; d = dst[e]; } else { s = e - EE; d = e - EE; }
    int pos = atomicAdd(&wptr[d], 1);
    colx[pos] = s;
}

// ---------------------------------------------------------------------------
// BF16 MFMA GEMM with fused epilogue (node-major outputs):
//   - hN[row][col] bf16  (node-major h, col = head*64 + c)
//   - aS[row][head], aD[row][head] fp32 (attention dots), H = N/64
// C[M,N] = A[Mpad,K] * Bt[N,K]^T. 128x128 tile, 4 waves, 16x16x32 MFMA.
// ---------------------------------------------------------------------------
__global__ __launch_bounds__(256) void gemm_bf16_fused(
        const unsigned short* __restrict__ A, const unsigned short* __restrict__ Bt,
        unsigned short* __restrict__ hN, float* __restrict__ aS, float* __restrict__ aD,
        const float* __restrict__ atts, const float* __restrict__ attd,
        int M, int N, int K) {
    __shared__ unsigned short As[128][40];
    __shared__ unsigned short Bs[128][40];
    const int t = threadIdx.x;
    const int lane = t & 63, wave = t >> 6;
    const int wm = wave >> 1, wn = wave & 1;
    const int quad = lane >> 4, mrow = lane & 15;
    const int row0 = blockIdx.y * 128, col0 = blockIdx.x * 128;
    const int srow = t >> 2, schunk = (t & 3) * 8;
    const int H = N >> 6;

    floatx4 acc[4][4];
#pragma unroll
    for (int i = 0; i < 4; ++i)
#pragma unroll
        for (int j = 0; j < 4; ++j)
#pragma unroll
            for (int r = 0; r < 4; ++r) acc[i][j][r] = 0.f;

    for (int k0 = 0; k0 < K; k0 += 32) {
        uint4 ra0 = *(const uint4*)(A  + (size_t)(row0 + srow)      * K + k0 + schunk);
        uint4 ra1 = *(const uint4*)(A  + (size_t)(row0 + srow + 64) * K + k0 + schunk);
        uint4 rb0 = *(const uint4*)(Bt + (size_t)(col0 + srow)      * K + k0 + schunk);
        uint4 rb1 = *(const uint4*)(Bt + (size_t)(col0 + srow + 64) * K + k0 + schunk);
        __syncthreads();
        *(uint4*)&As[srow][schunk]      = ra0;
        *(uint4*)&As[srow + 64][schunk] = ra1;
        *(uint4*)&Bs[srow][schunk]      = rb0;
        *(uint4*)&Bs[srow + 64][schunk] = rb1;
        __syncthreads();

        short8 af[4], bfr[4];
#pragma unroll
        for (int i = 0; i < 4; ++i)
            af[i] = *(const short8*)&As[wm * 64 + i * 16 + mrow][quad * 8];
#pragma unroll
        for (int j = 0; j < 4; ++j)
            bfr[j] = *(const short8*)&Bs[wn * 64 + j * 16 + mrow][quad * 8];
#pragma unroll
        for (int i = 0; i < 4; ++i)
#pragma unroll
            for (int j = 0; j < 4; ++j)
                acc[i][j] = __builtin_amdgcn_mfma_f32_16x16x32_bf16(af[i], bfr[j], acc[i][j], 0, 0, 0);
    }

    // ---- fused epilogue ----
    const int head = (col0 + wn * 64) >> 6;
    float attS[4], attD[4];
#pragma unroll
    for (int j = 0; j < 4; ++j) {
        attS[j] = atts[head * 64 + j * 16 + mrow];
        attD[j] = attd[head * 64 + j * 16 + mrow];
    }

#pragma unroll
    for (int i = 0; i < 4; ++i) {
#pragma unroll
        for (int r = 0; r < 4; ++r) {
            int row = row0 + wm * 64 + i * 16 + quad * 4 + r;
            float ps = acc[i][0][r] * attS[0] + acc[i][1][r] * attS[1]
                     + acc[i][2][r] * attS[2] + acc[i][3][r] * attS[3];
            float pd = acc[i][0][r] * attD[0] + acc[i][1][r] * attD[1]
                     + acc[i][2][r] * attD[2] + acc[i][3][r] * attD[3];
#pragma unroll
            for (int o = 1; o < 16; o <<= 1) {
                ps += __shfl_xor(ps, o);
                pd += __shfl_xor(pd, o);
            }
            if (row < M) {
                if (mrow == 0) {
                    aS[(size_t)row * H + head] = ps;
                    aD[(size_t)row * H + head] = pd;
                }
#pragma unroll
                for (int j = 0; j < 4; ++j)
                    hN[(size_t)row * N + col0 + wn * 64 + j * 16 + mrow] = f2bf(acc[i][j][r]);
            }
        }
    }
}

// ---------------------------------------------------------------------------
// GAT aggregation, all heads per wave. One wave per dst node, 4 waves/block.
// ---------------------------------------------------------------------------
template <int H>
__global__ __launch_bounds__(256) void gat_agg_all(
        const unsigned short* __restrict__ hN,
        const float* __restrict__ aS, const float* __restrict__ aD,
        const int* __restrict__ rowp, const int* __restrict__ colx,
        const float* __restrict__ bias, float* __restrict__ out, int Nn) {
    constexpr int F = H * 64;
    __shared__ float pbuf[4][64 * H];
    __shared__ int   snbuf[4][64];
    const int wave = threadIdx.x >> 6, lane = threadIdx.x & 63;
    const int n = blockIdx.x * 4 + wave;
    if (n >= Nn) return;
    const int hd = (lane * H) >> 6;       // this lane's head
    const int chbase = lane * H;          // flat channel base

    const int b0 = rowp[n], b1 = rowp[n + 1];

    float adv[H];
#pragma unroll
    for (int h = 0; h < H; ++h) adv[h] = aD[(size_t)n * H + h];   // broadcast

    // ---- pass 1: per-head m, s ----
    float m[H], s[H];
#pragma unroll
    for (int h = 0; h < H; ++h) { m[h] = -1e30f; s[h] = 0.f; }
    for (int c0 = b0; c0 < b1; c0 += 64) {
        int cnt = min(64, b1 - c0);
        float e[H];
#pragma unroll
        for (int h = 0; h < H; ++h) e[h] = -1e30f;
        if (lane < cnt) {
            int sn = colx[c0 + lane];
#pragma unroll
            for (int h = 0; h < H; ++h) {
                float tt = aS[(size_t)sn * H + h] + adv[h];
                e[h] = (tt > 0.f) ? tt : 0.2f * tt;
            }
        }
#pragma unroll
        for (int h = 0; h < H; ++h) {
            float mc = e[h];
#pragma unroll
            for (int o = 32; o > 0; o >>= 1) mc = fmaxf(mc, __shfl_xor(mc, o));
            float nm = fmaxf(m[h], mc);
            s[h] *= __expf(m[h] - nm);
            float p = (lane < cnt) ? __expf(e[h] - nm) : 0.f;
#pragma unroll
            for (int o = 32; o > 0; o >>= 1) p += __shfl_xor(p, o);
            s[h] += p; m[h] = nm;
        }
    }
    float inv[H];
#pragma unroll
    for (int h = 0; h < H; ++h) inv[h] = 1.f / s[h];

    // ---- pass 2: probs -> LDS, coalesced gather ----
    float acc[H];
#pragma unroll
    for (int h = 0; h < H; ++h) acc[h] = 0.f;

    for (int c0 = b0; c0 < b1; c0 += 64) {
        int cnt = min(64, b1 - c0);
        if (lane < cnt) {
            int sn = colx[c0 + lane];
            snbuf[wave][lane] = sn;
#pragma unroll
            for (int h = 0; h < H; ++h) {
                float tt = aS[(size_t)sn * H + h] + adv[h];
                tt = (tt > 0.f) ? tt : 0.2f * tt;
                pbuf[wave][lane * H + h] = __expf(tt - m[h]) * inv[h];
            }
        }
        __threadfence_block();   // LDS writes visible before reads (intra-wave)

        int j = 0;
        for (; j + 4 <= cnt; j += 4) {
            int s0 = snbuf[wave][j],     s1 = snbuf[wave][j + 1];
            int s2 = snbuf[wave][j + 2], s3 = snbuf[wave][j + 3];
            float p0 = pbuf[wave][(j + 0) * H + hd];
            float p1 = pbuf[wave][(j + 1) * H + hd];
            float p2 = pbuf[wave][(j + 2) * H + hd];
            float p3 = pbuf[wave][(j + 3) * H + hd];
            const unsigned* r0 = (const unsigned*)(hN + (size_t)s0 * F + chbase);
            const unsigned* r1 = (const unsigned*)(hN + (size_t)s1 * F + chbase);
            const unsigned* r2 = (const unsigned*)(hN + (size_t)s2 * F + chbase);
            const unsigned* r3 = (const unsigned*)(hN + (size_t)s3 * F + chbase);
#pragma unroll
            for (int k = 0; k < H / 2; ++k) {
                unsigned u0 = r0[k], u1 = r1[k], u2 = r2[k], u3 = r3[k];
                acc[2 * k]     += p0 * bflo(u0) + p1 * bflo(u1) + p2 * bflo(u2) + p3 * bflo(u3);
                acc[2 * k + 1] += p0 * bfhi(u0) + p1 * bfhi(u1) + p2 * bfhi(u2) + p3 * bfhi(u3);
            }
        }
        for (; j < cnt; ++j) {
            int sj = snbuf[wave][j];
            float pj = pbuf[wave][j * H + hd];
            const unsigned* rr = (const unsigned*)(hN + (size_t)sj * F + chbase);
#pragma unroll
            for (int k = 0; k < H / 2; ++k) {
                unsigned u = rr[k];
                acc[2 * k]     += pj * bflo(u);
                acc[2 * k + 1] += pj * bfhi(u);
            }
        }
        __threadfence_block();   // reads done before next chunk overwrites
    }

#pragma unroll
    for (int h = 0; h < H; ++h)
        out[(size_t)n * F + chbase + h] = acc[h] + bias[chbase + h];
}

// ---------------------------------------------------------------------------
// FP32 tiled GEMM for layer 4 (N=16) -> writes bf16 hN (single head, C=16)
// ---------------------------------------------------------------------------
__global__ __launch_bounds__(256) void gemm_f32_bf16out(const float* __restrict__ A,
                                                        const float* __restrict__ B,
                                                        unsigned short* __restrict__ C,
                                                        int M, int N, int K) {
    __shared__ float As[16][65];
    __shared__ float Bs[16][64];
    const int tid = threadIdx.x;
    const int tx = tid & 15, ty = tid >> 4;
    const int row0 = blockIdx.y * 64, col0 = blockIdx.x * 64;
    const int rA = tid >> 2, kq = (tid & 3) << 2;
    const int rB = tid >> 4, cq = (tid & 15) << 2;
    float acc[4][4] = {};

    for (int k0 = 0; k0 < K; k0 += 16) {
        float4 fa = make_float4(0.f, 0.f, 0.f, 0.f);
        int arow = row0 + rA;
        if (arow < M) fa = *(const float4*)(A + (size_t)arow * K + k0 + kq);
        float4 fb = make_float4(0.f, 0.f, 0.f, 0.f);
        int bcol = col0 + cq;
        if (bcol < N) fb = *(const float4*)(B + (size_t)(k0 + rB) * N + bcol);
        As[kq + 0][rA] = fa.x; As[kq + 1][rA] = fa.y;
        As[kq + 2][rA] = fa.z; As[kq + 3][rA] = fa.w;
        *(float4*)&Bs[rB][cq] = fb;
        __syncthreads();
#pragma unroll
        for (int k = 0; k < 16; ++k) {
            float a0 = As[k][ty * 4 + 0];
            float a1 = As[k][ty * 4 + 1];
            float a2 = As[k][ty * 4 + 2];
            float a3 = As[k][ty * 4 + 3];
            float4 b = *(float4*)&Bs[k][tx * 4];
            acc[0][0] += a0 * b.x; acc[0][1] += a0 * b.y; acc[0][2] += a0 * b.z; acc[0][3] += a0 * b.w;
            acc[1][0] += a1 * b.x; acc[1][1] += a1 * b.y; acc[1][2] += a1 * b.z; acc[1][3] += a1 * b.w;
            acc[2][0] += a2 * b.x; acc[2][1] += a2 * b.y; acc[2][2] += a2 * b.z; acc[2][3] += a2 * b.w;
            acc[3][0] += a3 * b.x; acc[3][1] += a3 * b.y; acc[3][2] += a3 * b.z; acc[3][3] += a3 * b.w;
        }
        __syncthreads();
    }
#pragma unroll
    for (int i = 0; i < 4; ++i) {
        int r = row0 + ty * 4 + i;
        if (r >= M) continue;
#pragma unroll
        for (int jj = 0; jj < 4; ++jj) {
            int c = col0 + tx * 4 + jj;
            if (c < N) C[(size_t)r * N + c] = f2bf(acc[i][jj]);
        }
    }
}

// ---------------------------------------------------------------------------
// Attention scores from bf16 h (layer 4 only): one wave per node, H=1.
// ---------------------------------------------------------------------------
template <int C>
__global__ void att_scores_bf(const unsigned short* __restrict__ h,
                              const float* __restrict__ atts, const float* __restrict__ attd,
                              float* __restrict__ aS, float* __restrict__ aD, int Nn) {
    int wid = (blockIdx.x * blockDim.x + threadIdx.x) >> 6;
    int lane = threadIdx.x & 63;
    if (wid >= Nn) return;
    float sv = 0.f, dv = 0.f;
    if (lane < C) {
        float v = bf2f(h[(size_t)wid * C + lane]);
        sv = v * atts[lane];
        dv = v * attd[lane];
    }
#pragma unroll
    for (int o = 32; o > 0; o >>= 1) {
        sv += __shfl_down(sv, o);
        dv += __shfl_down(dv, o);
    }
    if (lane == 0) { aS[wid] = sv; aD[wid] = dv; }
}

// ---------------------------------------------------------------------------
// GAT aggregation for layer 4 (H=1, C=16): per-(dst)-wave flash-style.
// ---------------------------------------------------------------------------
template <int H, int C>
__global__ void gat_agg_bf(const unsigned short* __restrict__ hT,
                           const float* __restrict__ aSt, const float* __restrict__ aDt,
                           const int* __restrict__ rowp, const int* __restrict__ colx,
                           const float* __restrict__ bias, float* __restrict__ out, int Nn) {
    int b = blockIdx.x;
    int head = b % H;
    int n = (b / H) * 4 + (threadIdx.x >> 6);
    int lane = threadIdx.x & 63;
    if (n >= Nn) return;
    const unsigned short* ht = hT + (size_t)head * Nn * C;
    const float* as = aSt + (size_t)head * Nn;
    float adv = aDt[(size_t)head * Nn + n];
    int b0 = rowp[n], b1 = rowp[n + 1];

    float m = -1e30f, s = 0.f, acc = 0.f;
    for (int c0 = b0; c0 < b1; c0 += 64) {
        int cnt = b1 - c0; if (cnt > 64) cnt = 64;
        int sn = 0; float e = -1e30f;
        if (lane < cnt) {
            sn = colx[c0 + lane];
            float tt = as[sn] + adv;
            e = (tt > 0.f) ? tt : 0.2f * tt;
        }
        float mc = e;
#pragma unroll
        for (int o = 32; o > 0; o >>= 1) mc = fmaxf(mc, __shfl_xor(mc, o));
        float nm = fmaxf(m, mc);
        float sc = __expf(m - nm);
        acc *= sc; s *= sc;
        float p = (lane < cnt) ? __expf(e - nm) : 0.f;
        float ps = p;
#pragma unroll
        for (int o = 32; o > 0; o >>= 1) ps += __shfl_xor(ps, o);
        s += ps; m = nm;

        int j = 0;
        for (; j + 4 <= cnt; j += 4) {
            int s0 = __shfl(sn, j),     s1 = __shfl(sn, j + 1);
            int s2 = __shfl(sn, j + 2), s3 = __shfl(sn, j + 3);
            float p0 = __shfl(p, j),     p1 = __shfl(p, j + 1);
            float p2 = __shfl(p, j + 2), p3 = __shfl(p, j + 3);
            float h0 = 0.f, h1 = 0.f, h2 = 0.f, h3 = 0.f;
            if (lane < C) {
                h0 = bf2f(ht[(size_t)s0 * C + lane]);
                h1 = bf2f(ht[(size_t)s1 * C + lane]);
                h2 = bf2f(ht[(size_t)s2 * C + lane]);
                h3 = bf2f(ht[(size_t)s3 * C + lane]);
            }
            acc += p0 * h0 + p1 * h1 + p2 * h2 + p3 * h3;
        }
        for (; j < cnt; ++j) {
            int sj = __shfl(sn, j);
            float pj = __shfl(p, j);
            float hv = (lane < C) ? bf2f(ht[(size_t)sj * C + lane]) : 0.f;
            acc += pj * hv;
        }
    }
    if (lane < C)
        out[(size_t)n * (H * C) + head * C + lane] = acc / s + bias[head * C + lane];
}

// ---------------------------------------------------------------------------
// BatchNorm stats, DETERMINISTIC two-stage (no float atomics):
// Stage 1: BNP blocks x 256 thr grid-stride; stride % F == 0 so each thread's
// 4 columns are fixed; fixed-order register accumulation + fixed LDS tree;
// block partial written to part[b][2F].
// Stage 2: F threads, each serially sums BNP partials (fixed order) and emits
// scale/shift. Fully replay-deterministic.
// ---------------------------------------------------------------------------
template <int F>
__global__ __launch_bounds__(256) void bn_stats_det(const float* __restrict__ x,
                                                    float* __restrict__ part,
                                                    long long total) {
    constexpr int R  = 1024 / F;    // column-set repeats per block
    constexpr int NT = F / 4;       // threads in final accumulation
    __shared__ float sd[256 * 9];
    const int t = threadIdx.x;
    long long idx = ((long long)blockIdx.x * 256 + t) * 4;
    const long long stride = (long long)gridDim.x * 1024;
    float s0 = 0, s1 = 0, s2 = 0, s3 = 0, q0 = 0, q1 = 0, q2 = 0, q3 = 0;
    for (; idx < total; idx += stride) {
        float4 v = *(const float4*)(x + idx);
        s0 += v.x; q0 += v.x * v.x;
        s1 += v.y; q1 += v.y * v.y;
        s2 += v.z; q2 += v.z * v.z;
        s3 += v.w; q3 += v.w * v.w;
    }
    sd[t * 9 + 0] = s0; sd[t * 9 + 1] = s1; sd[t * 9 + 2] = s2; sd[t * 9 + 3] = s3;
    sd[t * 9 + 4] = q0; sd[t * 9 + 5] = q1; sd[t * 9 + 6] = q2; sd[t * 9 + 7] = q3;
    __syncthreads();
    if (t < NT) {
        float a[8];
#pragma unroll
        for (int k = 0; k < 8; ++k) a[k] = sd[t * 9 + k];
        for (int r = 1; r < R; ++r)
#pragma unroll
            for (int k = 0; k < 8; ++k) a[k] += sd[(t + r * NT) * 9 + k];
        int col = t * 4;
        float* pb = part + (size_t)blockIdx.x * 2 * F;
#pragma unroll
        for (int k = 0; k < 4; ++k) {
            pb[col + k]     = a[k];
            pb[F + col + k] = a[4 + k];
        }
    }
}

__global__ void bn_reduce_final(const float* __restrict__ part, const float* __restrict__ gamma,
                                const float* __restrict__ beta, float* __restrict__ ss,
                                int F, int P, float invN) {
    int c = blockIdx.x * blockDim.x + threadIdx.x;
    if (c >= F) return;
    float s = 0.f, q = 0.f;
    for (int p = 0; p < P; ++p) {
        s += part[(size_t)p * 2 * F + c];
        q += part[(size_t)p * 2 * F + F + c];
    }
    float mu = s * invN;
    float var = q * invN - mu * mu;
    float sc = gamma[c] * rsqrtf(var + 1e-5f);
    ss[c] = sc;
    ss[F + c] = beta[c] - mu * sc;
}

__global__ void bn_apply_elu_bf16(const float* __restrict__ x, const float* __restrict__ ss,
                                  unsigned short* __restrict__ outA,
                                  int Nn, int F, int fmask) {
    long long idx4 = ((long long)blockIdx.x * blockDim.x + threadIdx.x) * 4;
    int row = (int)(idx4 / F);
    ushort4 o = make_ushort4(0, 0, 0, 0);
    if (row < Nn) {
        int c = (int)(idx4 & fmask);
        float4 v = *(const float4*)(x + idx4);
        float v0 = v.x * ss[c + 0] + ss[F + c + 0];
        float v1 = v.y * ss[c + 1] + ss[F + c + 1];
        float v2 = v.z * ss[c + 2] + ss[F + c + 2];
        float v3 = v.w * ss[c + 3] + ss[F + c + 3];
        v0 = (v0 > 0.f) ? v0 : (__expf(v0) - 1.f);
        v1 = (v1 > 0.f) ? v1 : (__expf(v1) - 1.f);
        v2 = (v2 > 0.f) ? v2 : (__expf(v2) - 1.f);
        v3 = (v3 > 0.f) ? v3 : (__expf(v3) - 1.f);
        o.x = f2bf(v0); o.y = f2bf(v1); o.z = f2bf(v2); o.w = f2bf(v3);
    }
    *(ushort4*)(outA + idx4) = o;
}

// log_softmax over 16 features per node
__global__ void log_softmax16(const float* __restrict__ x, float* __restrict__ out, int Nn) {
    int n = blockIdx.x * blockDim.x + threadIdx.x;
    if (n >= Nn) return;
    float v[16];
    float m = -1e30f;
#pragma unroll
    for (int i = 0; i < 16; ++i) { v[i] = x[n * 16 + i]; m = fmaxf(m, v[i]); }
    float s = 0.f;
#pragma unroll
    for (int i = 0; i < 16; ++i) s += __expf(v[i] - m);
    float l = __logf(s) + m;
#pragma unroll
    for (int i = 0; i < 16; ++i) out[n * 16 + i] = v[i] - l;
}

// ---------------------------------------------------------------------------
// Launcher
// ---------------------------------------------------------------------------
extern "C" void kernel_launch(void* const* d_in, const int* in_sizes, int n_in,
                              void* d_out, int out_size, void* d_ws, size_t ws_size,
                              hipStream_t stream) {
    const float* x   = (const float*)d_in[0];
    const int*   ei  = (const int*)d_in[1];
    const float* W1  = (const float*)d_in[2];
    const float* as1 = (const float*)d_in[3];
    const float* ad1 = (const float*)d_in[4];
    const float* b1  = (const float*)d_in[5];
    const float* ga1 = (const float*)d_in[6];
    const float* be1 = (const float*)d_in[7];
    const float* W2  = (const float*)d_in[8];
    const float* as2 = (const float*)d_in[9];
    const float* ad2 = (const float*)d_in[10];
    const float* b2  = (const float*)d_in[11];
    const float* ga2 = (const float*)d_in[12];
    const float* be2 = (const float*)d_in[13];
    const float* W3  = (const float*)d_in[14];
    const float* as3 = (const float*)d_in[15];
    const float* ad3 = (const float*)d_in[16];
    const float* b3  = (const float*)d_in[17];
    const float* ga3 = (const float*)d_in[18];
    const float* be3 = (const float*)d_in[19];
    const float* W4  = (const float*)d_in[20];
    const float* as4 = (const float*)d_in[21];
    const float* ad4 = (const float*)d_in[22];
    const float* b4  = (const float*)d_in[23];
    float* outp = (float*)d_out;

    uint8_t* base = (uint8_t*)d_ws;
    size_t off = 0;
    auto alloc = [&](size_t nbytes) -> void* {
        off = (off + 255) & ~(size_t)255;
        void* p = base + off;
        off += nbytes;
        return p;
    };
    float* bufO = (float*)alloc((size_t)NN * 512 * 4);                       // agg out (fp32, BN in)
    unsigned short* bufA = (unsigned short*)alloc((size_t)MPAD * 512 * 2);   // bf16 GEMM A
    unsigned short* hN   = (unsigned short*)alloc((size_t)NN * 512 * 2);     // bf16 node-major h
    unsigned short* Wt1  = (unsigned short*)alloc((size_t)512 * 512 * 2);
    unsigned short* Wt2  = (unsigned short*)alloc((size_t)256 * 512 * 2);
    unsigned short* Wt3  = (unsigned short*)alloc((size_t)128 * 256 * 2);
    float* aSn  = (float*)alloc((size_t)NN * 8 * 4);
    float* aDn  = (float*)alloc((size_t)NN * 8 * 4);
    int*   cnt  = (int*)alloc((size_t)NN * 4);
    int*   rowp = (int*)alloc((size_t)(NN + 1) * 4);
    int*   wptr = (int*)alloc((size_t)NN * 4);
    int*   colx = (int*)alloc((size_t)ET * 4);
    float* bnp  = (float*)alloc((size_t)BNP * 1024 * 4);     // BN partials [BNP][2F]
    float* bns  = (float*)alloc((size_t)1024 * 4);           // scale/shift

    const int* srcRow = ei;
    const int* dstRow = ei + EE;

    // ---- CSR build ----
    zero_i32<<<(NN + 255) / 256, 256, 0, stream>>>(cnt, NN);
    count_edges<<<(ET + 255) / 256, 256, 0, stream>>>(dstRow, cnt);
    scan20k<<<1, 1024, 0, stream>>>(cnt, rowp, wptr, NN);
    fill_edges<<<(ET + 255) / 256, 256, 0, stream>>>(srcRow, dstRow, wptr, colx);

    // ---- Weight transposes+casts (once) ----
    cvt_w_t<<<(512 * 512 + 255) / 256, 256, 0, stream>>>(W1, Wt1, 512, 512);
    cvt_w_t<<<(512 * 256 + 255) / 256, 256, 0, stream>>>(W2, Wt2, 512, 256);
    cvt_w_t<<<(256 * 128 + 255) / 256, 256, 0, stream>>>(W3, Wt3, 256, 128);

    // ---- Layer 1: Fin=512, H=8, C=64 (F=512) ----
    {
        cvt_a_bf16<<<((MPAD * 512 / 4) + 255) / 256, 256, 0, stream>>>(x, bufA, NN, MPAD, 512);
        dim3 g(512 / 128, MPAD / 128);
        gemm_bf16_fused<<<g, 256, 0, stream>>>(bufA, Wt1, hN, aSn, aDn, as1, ad1, NN, 512, 512);
        gat_agg_all<8><<<NN / 4, 256, 0, stream>>>(hN, aSn, aDn, rowp, colx, b1, bufO, NN);
        bn_stats_det<512><<<BNP, 256, 0, stream>>>(bufO, bnp, (long long)NN * 512);
        bn_reduce_final<<<2, 256, 0, stream>>>(bnp, ga1, be1, bns, 512, BNP, 1.0f / NN);
        bn_apply_elu_bf16<<<(MPAD * 512 / 4) / 256, 256, 0, stream>>>(bufO, bns, bufA, NN, 512, 511);
    }
    // ---- Layer 2: Fin=512, H=4, C=64 (F=256) ----
    {
        dim3 g(256 / 128, MPAD / 128);
        gemm_bf16_fused<<<g, 256, 0, stream>>>(bufA, Wt2, hN, aSn, aDn, as2, ad2, NN, 256, 512);
        gat_agg_all<4><<<NN / 4, 256, 0, stream>>>(hN, aSn, aDn, rowp, colx, b2, bufO, NN);
        bn_stats_det<256><<<BNP, 256, 0, stream>>>(bufO, bnp, (long long)NN * 256);
        bn_reduce_final<<<1, 256, 0, stream>>>(bnp, ga2, be2, bns, 256, BNP, 1.0f / NN);
        bn_apply_elu_bf16<<<(MPAD * 256 / 4) / 256, 256, 0, stream>>>(bufO, bns, bufA, NN, 256, 255);
    }
    // ---- Layer 3: Fin=256, H=2, C=64 (F=128) ----
    {
        dim3 g(128 / 128, MPAD / 128);
        gemm_bf16_fused<<<g, 256, 0, stream>>>(bufA, Wt3, hN, aSn, aDn, as3, ad3, NN, 128, 256);
        gat_agg_all<2><<<NN / 4, 256, 0, stream>>>(hN, aSn, aDn, rowp, colx, b3, bufO, NN);
        bn_stats_det<128><<<BNP, 256, 0, stream>>>(bufO, bnp, (long long)NN * 128);
        bn_reduce_final<<<1, 128, 0, stream>>>(bnp, ga3, be3, bns, 128, BNP, 1.0f / NN);
        bn_apply_elu_bf16<<<(MPAD * 128 / 4) / 256, 256, 0, stream>>>(bufO, bns, bufA, NN, 128, 127);
    }
    // ---- Layer 4: Fin=128, H=1, C=16 (F=16) + log_softmax ----
    {
        bf2f_kernel<<<(int)(((long long)NN * 128 / 4 + 255) / 256), 256, 0, stream>>>(
            bufA, bufO, (long long)NN * 128);
        dim3 g((16 + 63) / 64, (NN + 63) / 64);
        gemm_f32_bf16out<<<g, 256, 0, stream>>>(bufO, W4, hN, NN, 16, 128);
        att_scores_bf<16><<<(NN + 3) / 4, 256, 0, stream>>>(hN, as4, ad4, aSn, aDn, NN);
        gat_agg_bf<1, 16><<<NN / 4, 256, 0, stream>>>(hN, aSn, aDn, rowp, colx, b4, bufO, NN);
        log_softmax16<<<(NN + 255) / 256, 256, 0, stream>>>(bufO, outp, NN);
    }
}

// Round 8
// 490.862 us; speedup vs baseline: 2.5799x; 1.3261x over previous
//
#include <hip/hip_runtime.h>
#include <hip/hip_bf16.h>
#include <cstdint>
#include <cstddef>

// Problem constants
#define NN 20000
#define EE 320000
#define ET (EE + NN)     // edges + self loops
#define MPAD 20096       // 157 * 128, M padded to tile
#define BNP 256          // BN stage-1 partial blocks (deterministic)

typedef __attribute__((ext_vector_type(8))) short  short8;   // 8 bf16 (4 VGPRs)
typedef __attribute__((ext_vector_type(4))) float  floatx4;  // MFMA C/D frag

__device__ inline unsigned short f2bf(float f) {   // RNE fp32 -> bf16
    unsigned u = __float_as_uint(f);
    u += 0x7FFFu + ((u >> 16) & 1u);
    return (unsigned short)(u >> 16);
}
__device__ inline float bf2f(unsigned short b) {
    return __uint_as_float(((unsigned)b) << 16);
}
// packed bf16x2 in a uint -> two floats
__device__ inline float bflo(unsigned u) { return __uint_as_float(u << 16); }
__device__ inline float bfhi(unsigned u) { return __uint_as_float(u & 0xFFFF0000u); }

// ---------------------------------------------------------------------------
// Utility kernels
// ---------------------------------------------------------------------------
__global__ void zero_i32(int* __restrict__ p, int n) {
    int i = blockIdx.x * blockDim.x + threadIdx.x;
    if (i < n) p[i] = 0;
}

__global__ void bf2f_kernel(const unsigned short* __restrict__ in, float* __restrict__ out,
                            long long n) {
    long long i = ((long long)blockIdx.x * blockDim.x + threadIdx.x) * 4;
    if (i >= n) return;
    ushort4 v = *(const ushort4*)(in + i);
    float4 o;
    o.x = bf2f(v.x); o.y = bf2f(v.y); o.z = bf2f(v.z); o.w = bf2f(v.w);
    *(float4*)(out + i) = o;
}

// fp32 [M,K] -> bf16 [Mpad,K], rows >= M zero-filled. 4 elems/thread.
__global__ void cvt_a_bf16(const float* __restrict__ in, unsigned short* __restrict__ out,
                           int M, int Mpad, int K) {
    long long base = ((long long)blockIdx.x * blockDim.x + threadIdx.x) * 4;
    if (base >= (long long)Mpad * K) return;
    int row = (int)(base / K);
    float4 v = make_float4(0.f, 0.f, 0.f, 0.f);
    if (row < M) v = *(const float4*)(in + base);
    ushort4 o;
    o.x = f2bf(v.x); o.y = f2bf(v.y); o.z = f2bf(v.z); o.w = f2bf(v.w);
    *(ushort4*)(out + base) = o;
}

// W [K,N] fp32 -> Wt [N,K] bf16 (once per launch; small)
__global__ void cvt_w_t(const float* __restrict__ W, unsigned short* __restrict__ Wt,
                        int K, int N) {
    int i = blockIdx.x * blockDim.x + threadIdx.x;
    if (i >= K * N) return;
    int k = i / N, n = i - k * N;
    Wt[(size_t)n * K + k] = f2bf(W[i]);
}

// ---------------------------------------------------------------------------
// CSR build: count -> scan -> fill   (dst-major CSR, built once per launch)
// ---------------------------------------------------------------------------
__global__ void count_edges(const int* __restrict__ dst, int* __restrict__ cnt) {
    int e = blockIdx.x * blockDim.x + threadIdx.x;
    if (e >= ET) return;
    int d = (e < EE) ? dst[e] : (e - EE);
    atomicAdd(&cnt[d], 1);
}

__global__ void scan20k(const int* __restrict__ cnt, int* __restrict__ rowp,
                        int* __restrict__ wptr, int n) {
    __shared__ int sd[1024];
    __shared__ int run;
    int t = threadIdx.x;
    if (t == 0) run = 0;
    __syncthreads();
    for (int base = 0; base < n; base += 1024) {
        int i = base + t;
        int v = (i < n) ? cnt[i] : 0;
        sd[t] = v;
        __syncthreads();
        for (int o = 1; o < 1024; o <<= 1) {
            int u = (t >= o) ? sd[t - o] : 0;
            __syncthreads();
            sd[t] += u;
            __syncthreads();
        }
        int incl = sd[t];
        int excl = incl - v;
        if (i < n) { int rp = run + excl; rowp[i] = rp; wptr[i] = rp; }
        __syncthreads();
        if (t == 1023) run += sd[1023];
        __syncthreads();
    }
    if (t == 0) rowp[n] = run;
}

__global__ void fill_edges(const int* __restrict__ src, const int* __restrict__ dst,
                           int* __restrict__ wptr, int* __restrict__ colx) {
    int e = blockIdx.x * blockDim.x + threadIdx.x;
    if (e >= ET) return;
    int s, d;
    if (e < EE) { s = src[e]; d = dst[e]; } else { s = e - EE; d = e - EE; }
    int pos = atomicAdd(&wptr[d], 1);
    colx[pos] = s;
}

// ---------------------------------------------------------------------------
// BF16 MFMA GEMM with fused epilogue (node-major outputs):
//   - hN[row][col] bf16  (node-major h, col = head*64 + c)
//   - aS[row][head], aD[row][head] fp32 (attention dots), H = N/64
// C[M,N] = A[Mpad,K] * Bt[N,K]^T. 128x128 tile, 4 waves, 16x16x32 MFMA.
// ---------------------------------------------------------------------------
__global__ __launch_bounds__(256) void gemm_bf16_fused(
        const unsigned short* __restrict__ A, const unsigned short* __restrict__ Bt,
        unsigned short* __restrict__ hN, float* __restrict__ aS, float* __restrict__ aD,
        const float* __restrict__ atts, const float* __restrict__ attd,
        int M, int N, int K) {
    __shared__ unsigned short As[128][40];
    __shared__ unsigned short Bs[128][40];
    const int t = threadIdx.x;
    const int lane = t & 63, wave = t >> 6;
    const int wm = wave >> 1, wn = wave & 1;
    const int quad = lane >> 4, mrow = lane & 15;
    const int row0 = blockIdx.y * 128, col0 = blockIdx.x * 128;
    const int srow = t >> 2, schunk = (t & 3) * 8;
    const int H = N >> 6;

    floatx4 acc[4][4];
#pragma unroll
    for (int i = 0; i < 4; ++i)
#pragma unroll
        for (int j = 0; j < 4; ++j)
#pragma unroll
            for (int r = 0; r < 4; ++r) acc[i][j][r] = 0.f;

    for (int k0 = 0; k0 < K; k0 += 32) {
        uint4 ra0 = *(const uint4*)(A  + (size_t)(row0 + srow)      * K + k0 + schunk);
        uint4 ra1 = *(const uint4*)(A  + (size_t)(row0 + srow + 64) * K + k0 + schunk);
        uint4 rb0 = *(const uint4*)(Bt + (size_t)(col0 + srow)      * K + k0 + schunk);
        uint4 rb1 = *(const uint4*)(Bt + (size_t)(col0 + srow + 64) * K + k0 + schunk);
        __syncthreads();
        *(uint4*)&As[srow][schunk]      = ra0;
        *(uint4*)&As[srow + 64][schunk] = ra1;
        *(uint4*)&Bs[srow][schunk]      = rb0;
        *(uint4*)&Bs[srow + 64][schunk] = rb1;
        __syncthreads();

        short8 af[4], bfr[4];
#pragma unroll
        for (int i = 0; i < 4; ++i)
            af[i] = *(const short8*)&As[wm * 64 + i * 16 + mrow][quad * 8];
#pragma unroll
        for (int j = 0; j < 4; ++j)
            bfr[j] = *(const short8*)&Bs[wn * 64 + j * 16 + mrow][quad * 8];
#pragma unroll
        for (int i = 0; i < 4; ++i)
#pragma unroll
            for (int j = 0; j < 4; ++j)
                acc[i][j] = __builtin_amdgcn_mfma_f32_16x16x32_bf16(af[i], bfr[j], acc[i][j], 0, 0, 0);
    }

    // ---- fused epilogue ----
    const int head = (col0 + wn * 64) >> 6;
    float attS[4], attD[4];
#pragma unroll
    for (int j = 0; j < 4; ++j) {
        attS[j] = atts[head * 64 + j * 16 + mrow];
        attD[j] = attd[head * 64 + j * 16 + mrow];
    }

#pragma unroll
    for (int i = 0; i < 4; ++i) {
#pragma unroll
        for (int r = 0; r < 4; ++r) {
            int row = row0 + wm * 64 + i * 16 + quad * 4 + r;
            float ps = acc[i][0][r] * attS[0] + acc[i][1][r] * attS[1]
                     + acc[i][2][r] * attS[2] + acc[i][3][r] * attS[3];
            float pd = acc[i][0][r] * attD[0] + acc[i][1][r] * attD[1]
                     + acc[i][2][r] * attD[2] + acc[i][3][r] * attD[3];
#pragma unroll
            for (int o = 1; o < 16; o <<= 1) {
                ps += __shfl_xor(ps, o);
                pd += __shfl_xor(pd, o);
            }
            if (row < M) {
                if (mrow == 0) {
                    aS[(size_t)row * H + head] = ps;
                    aD[(size_t)row * H + head] = pd;
                }
#pragma unroll
                for (int j = 0; j < 4; ++j)
                    hN[(size_t)row * N + col0 + wn * 64 + j * 16 + mrow] = f2bf(acc[i][j][r]);
            }
        }
    }
}

// ---------------------------------------------------------------------------
// GAT aggregation, all heads per wave. One wave per dst node, 4 waves/block.
// ---------------------------------------------------------------------------
template <int H>
__global__ __launch_bounds__(256) void gat_agg_all(
        const unsigned short* __restrict__ hN,
        const float* __restrict__ aS, const float* __restrict__ aD,
        const int* __restrict__ rowp, const int* __restrict__ colx,
        const float* __restrict__ bias, float* __restrict__ out, int Nn) {
    constexpr int F = H * 64;
    __shared__ float pbuf[4][64 * H];
    __shared__ int   snbuf[4][64];
    const int wave = threadIdx.x >> 6, lane = threadIdx.x & 63;
    const int n = blockIdx.x * 4 + wave;
    if (n >= Nn) return;
    const int hd = (lane * H) >> 6;       // this lane's head
    const int chbase = lane * H;          // flat channel base

    const int b0 = rowp[n], b1 = rowp[n + 1];

    float adv[H];
#pragma unroll
    for (int h = 0; h < H; ++h) adv[h] = aD[(size_t)n * H + h];   // broadcast

    // ---- pass 1: per-head m, s ----
    float m[H], s[H];
#pragma unroll
    for (int h = 0; h < H; ++h) { m[h] = -1e30f; s[h] = 0.f; }
    for (int c0 = b0; c0 < b1; c0 += 64) {
        int cnt = min(64, b1 - c0);
        float e[H];
#pragma unroll
        for (int h = 0; h < H; ++h) e[h] = -1e30f;
        if (lane < cnt) {
            int sn = colx[c0 + lane];
#pragma unroll
            for (int h = 0; h < H; ++h) {
                float tt = aS[(size_t)sn * H + h] + adv[h];
                e[h] = (tt > 0.f) ? tt : 0.2f * tt;
            }
        }
#pragma unroll
        for (int h = 0; h < H; ++h) {
            float mc = e[h];
#pragma unroll
            for (int o = 32; o > 0; o >>= 1) mc = fmaxf(mc, __shfl_xor(mc, o));
            float nm = fmaxf(m[h], mc);
            s[h] *= __expf(m[h] - nm);
            float p = (lane < cnt) ? __expf(e[h] - nm) : 0.f;
#pragma unroll
            for (int o = 32; o > 0; o >>= 1) p += __shfl_xor(p, o);
            s[h] += p; m[h] = nm;
        }
    }
    float inv[H];
#pragma unroll
    for (int h = 0; h < H; ++h) inv[h] = 1.f / s[h];

    // ---- pass 2: probs -> LDS, coalesced gather ----
    float acc[H];
#pragma unroll
    for (int h = 0; h < H; ++h) acc[h] = 0.f;

    for (int c0 = b0; c0 < b1; c0 += 64) {
        int cnt = min(64, b1 - c0);
        if (lane < cnt) {
            int sn = colx[c0 + lane];
            snbuf[wave][lane] = sn;
#pragma unroll
            for (int h = 0; h < H; ++h) {
                float tt = aS[(size_t)sn * H + h] + adv[h];
                tt = (tt > 0.f) ? tt : 0.2f * tt;
                pbuf[wave][lane * H + h] = __expf(tt - m[h]) * inv[h];
            }
        }
        __threadfence_block();   // LDS writes visible before reads (intra-wave)

        int j = 0;
        for (; j + 4 <= cnt; j += 4) {
            int s0 = snbuf[wave][j],     s1 = snbuf[wave][j + 1];
            int s2 = snbuf[wave][j + 2], s3 = snbuf[wave][j + 3];
            float p0 = pbuf[wave][(j + 0) * H + hd];
            float p1 = pbuf[wave][(j + 1) * H + hd];
            float p2 = pbuf[wave][(j + 2) * H + hd];
            float p3 = pbuf[wave][(j + 3) * H + hd];
            const unsigned* r0 = (const unsigned*)(hN + (size_t)s0 * F + chbase);
            const unsigned* r1 = (const unsigned*)(hN + (size_t)s1 * F + chbase);
            const unsigned* r2 = (const unsigned*)(hN + (size_t)s2 * F + chbase);
            const unsigned* r3 = (const unsigned*)(hN + (size_t)s3 * F + chbase);
#pragma unroll
            for (int k = 0; k < H / 2; ++k) {
                unsigned u0 = r0[k], u1 = r1[k], u2 = r2[k], u3 = r3[k];
                acc[2 * k]     += p0 * bflo(u0) + p1 * bflo(u1) + p2 * bflo(u2) + p3 * bflo(u3);
                acc[2 * k + 1] += p0 * bfhi(u0) + p1 * bfhi(u1) + p2 * bfhi(u2) + p3 * bfhi(u3);
            }
        }
        for (; j < cnt; ++j) {
            int sj = snbuf[wave][j];
            float pj = pbuf[wave][j * H + hd];
            const unsigned* rr = (const unsigned*)(hN + (size_t)sj * F + chbase);
#pragma unroll
            for (int k = 0; k < H / 2; ++k) {
                unsigned u = rr[k];
                acc[2 * k]     += pj * bflo(u);
                acc[2 * k + 1] += pj * bfhi(u);
            }
        }
        __threadfence_block();   // reads done before next chunk overwrites
    }

#pragma unroll
    for (int h = 0; h < H; ++h)
        out[(size_t)n * F + chbase + h] = acc[h] + bias[chbase + h];
}

// ---------------------------------------------------------------------------
// FP32 tiled GEMM for layer 4 (N=16) -> writes bf16 hN (single head, C=16)
// ---------------------------------------------------------------------------
__global__ __launch_bounds__(256) void gemm_f32_bf16out(const float* __restrict__ A,
                                                        const float* __restrict__ B,
                                                        unsigned short* __restrict__ C,
                                                        int M, int N, int K) {
    __shared__ float As[16][65];
    __shared__ float Bs[16][64];
    const int tid = threadIdx.x;
    const int tx = tid & 15, ty = tid >> 4;
    const int row0 = blockIdx.y * 64, col0 = blockIdx.x * 64;
    const int rA = tid >> 2, kq = (tid & 3) << 2;
    const int rB = tid >> 4, cq = (tid & 15) << 2;
    float acc[4][4] = {};

    for (int k0 = 0; k0 < K; k0 += 16) {
        float4 fa = make_float4(0.f, 0.f, 0.f, 0.f);
        int arow = row0 + rA;
        if (arow < M) fa = *(const float4*)(A + (size_t)arow * K + k0 + kq);
        float4 fb = make_float4(0.f, 0.f, 0.f, 0.f);
        int bcol = col0 + cq;
        if (bcol < N) fb = *(const float4*)(B + (size_t)(k0 + rB) * N + bcol);
        As[kq + 0][rA] = fa.x; As[kq + 1][rA] = fa.y;
        As[kq + 2][rA] = fa.z; As[kq + 3][rA] = fa.w;
        *(float4*)&Bs[rB][cq] = fb;
        __syncthreads();
#pragma unroll
        for (int k = 0; k < 16; ++k) {
            float a0 = As[k][ty * 4 + 0];
            float a1 = As[k][ty * 4 + 1];
            float a2 = As[k][ty * 4 + 2];
            float a3 = As[k][ty * 4 + 3];
            float4 b = *(float4*)&Bs[k][tx * 4];
            acc[0][0] += a0 * b.x; acc[0][1] += a0 * b.y; acc[0][2] += a0 * b.z; acc[0][3] += a0 * b.w;
            acc[1][0] += a1 * b.x; acc[1][1] += a1 * b.y; acc[1][2] += a1 * b.z; acc[1][3] += a1 * b.w;
            acc[2][0] += a2 * b.x; acc[2][1] += a2 * b.y; acc[2][2] += a2 * b.z; acc[2][3] += a2 * b.w;
            acc[3][0] += a3 * b.x; acc[3][1] += a3 * b.y; acc[3][2] += a3 * b.z; acc[3][3] += a3 * b.w;
        }
        __syncthreads();
    }
#pragma unroll
    for (int i = 0; i < 4; ++i) {
        int r = row0 + ty * 4 + i;
        if (r >= M) continue;
#pragma unroll
        for (int jj = 0; jj < 4; ++jj) {
            int c = col0 + tx * 4 + jj;
            if (c < N) C[(size_t)r * N + c] = f2bf(acc[i][jj]);
        }
    }
}

// ---------------------------------------------------------------------------
// Attention scores from bf16 h (layer 4 only): one wave per node, H=1.
// ---------------------------------------------------------------------------
template <int C>
__global__ void att_scores_bf(const unsigned short* __restrict__ h,
                              const float* __restrict__ atts, const float* __restrict__ attd,
                              float* __restrict__ aS, float* __restrict__ aD, int Nn) {
    int wid = (blockIdx.x * blockDim.x + threadIdx.x) >> 6;
    int lane = threadIdx.x & 63;
    if (wid >= Nn) return;
    float sv = 0.f, dv = 0.f;
    if (lane < C) {
        float v = bf2f(h[(size_t)wid * C + lane]);
        sv = v * atts[lane];
        dv = v * attd[lane];
    }
#pragma unroll
    for (int o = 32; o > 0; o >>= 1) {
        sv += __shfl_down(sv, o);
        dv += __shfl_down(dv, o);
    }
    if (lane == 0) { aS[wid] = sv; aD[wid] = dv; }
}

// ---------------------------------------------------------------------------
// GAT aggregation for layer 4 (H=1, C=16): per-(dst)-wave flash-style.
// ---------------------------------------------------------------------------
template <int H, int C>
__global__ void gat_agg_bf(const unsigned short* __restrict__ hT,
                           const float* __restrict__ aSt, const float* __restrict__ aDt,
                           const int* __restrict__ rowp, const int* __restrict__ colx,
                           const float* __restrict__ bias, float* __restrict__ out, int Nn) {
    int b = blockIdx.x;
    int head = b % H;
    int n = (b / H) * 4 + (threadIdx.x >> 6);
    int lane = threadIdx.x & 63;
    if (n >= Nn) return;
    const unsigned short* ht = hT + (size_t)head * Nn * C;
    const float* as = aSt + (size_t)head * Nn;
    float adv = aDt[(size_t)head * Nn + n];
    int b0 = rowp[n], b1 = rowp[n + 1];

    float m = -1e30f, s = 0.f, acc = 0.f;
    for (int c0 = b0; c0 < b1; c0 += 64) {
        int cnt = b1 - c0; if (cnt > 64) cnt = 64;
        int sn = 0; float e = -1e30f;
        if (lane < cnt) {
            sn = colx[c0 + lane];
            float tt = as[sn] + adv;
            e = (tt > 0.f) ? tt : 0.2f * tt;
        }
        float mc = e;
#pragma unroll
        for (int o = 32; o > 0; o >>= 1) mc = fmaxf(mc, __shfl_xor(mc, o));
        float nm = fmaxf(m, mc);
        float sc = __expf(m - nm);
        acc *= sc; s *= sc;
        float p = (lane < cnt) ? __expf(e - nm) : 0.f;
        float ps = p;
#pragma unroll
        for (int o = 32; o > 0; o >>= 1) ps += __shfl_xor(ps, o);
        s += ps; m = nm;

        int j = 0;
        for (; j + 4 <= cnt; j += 4) {
            int s0 = __shfl(sn, j),     s1 = __shfl(sn, j + 1);
            int s2 = __shfl(sn, j + 2), s3 = __shfl(sn, j + 3);
            float p0 = __shfl(p, j),     p1 = __shfl(p, j + 1);
            float p2 = __shfl(p, j + 2), p3 = __shfl(p, j + 3);
            float h0 = 0.f, h1 = 0.f, h2 = 0.f, h3 = 0.f;
            if (lane < C) {
                h0 = bf2f(ht[(size_t)s0 * C + lane]);
                h1 = bf2f(ht[(size_t)s1 * C + lane]);
                h2 = bf2f(ht[(size_t)s2 * C + lane]);
                h3 = bf2f(ht[(size_t)s3 * C + lane]);
            }
            acc += p0 * h0 + p1 * h1 + p2 * h2 + p3 * h3;
        }
        for (; j < cnt; ++j) {
            int sj = __shfl(sn, j);
            float pj = __shfl(p, j);
            float hv = (lane < C) ? bf2f(ht[(size_t)sj * C + lane]) : 0.f;
            acc += pj * hv;
        }
    }
    if (lane < C)
        out[(size_t)n * (H * C) + head * C + lane] = acc / s + bias[head * C + lane];
}

// ---------------------------------------------------------------------------
// BatchNorm stats, DETERMINISTIC two-stage (no float atomics):
// Stage 1: BNP blocks x 256 thr grid-stride; fixed-order accumulation;
// block partial -> part[b][2F].
// Stage 2 (parallel): grid = F/16 blocks x 256 thr = 8 p-rows x 32 targets
// (16 sum cols + 16 sumsq cols). Fixed-order serial row tree. Deterministic.
// ---------------------------------------------------------------------------
template <int F>
__global__ __launch_bounds__(256) void bn_stats_det(const float* __restrict__ x,
                                                    float* __restrict__ part,
                                                    long long total) {
    constexpr int R  = 1024 / F;    // column-set repeats per block
    constexpr int NT = F / 4;       // threads in final accumulation
    __shared__ float sd[256 * 9];
    const int t = threadIdx.x;
    long long idx = ((long long)blockIdx.x * 256 + t) * 4;
    const long long stride = (long long)gridDim.x * 1024;
    float s0 = 0, s1 = 0, s2 = 0, s3 = 0, q0 = 0, q1 = 0, q2 = 0, q3 = 0;
    for (; idx < total; idx += stride) {
        float4 v = *(const float4*)(x + idx);
        s0 += v.x; q0 += v.x * v.x;
        s1 += v.y; q1 += v.y * v.y;
        s2 += v.z; q2 += v.z * v.z;
        s3 += v.w; q3 += v.w * v.w;
    }
    sd[t * 9 + 0] = s0; sd[t * 9 + 1] = s1; sd[t * 9 + 2] = s2; sd[t * 9 + 3] = s3;
    sd[t * 9 + 4] = q0; sd[t * 9 + 5] = q1; sd[t * 9 + 6] = q2; sd[t * 9 + 7] = q3;
    __syncthreads();
    if (t < NT) {
        float a[8];
#pragma unroll
        for (int k = 0; k < 8; ++k) a[k] = sd[t * 9 + k];
        for (int r = 1; r < R; ++r)
#pragma unroll
            for (int k = 0; k < 8; ++k) a[k] += sd[(t + r * NT) * 9 + k];
        int col = t * 4;
        float* pb = part + (size_t)blockIdx.x * 2 * F;
#pragma unroll
        for (int k = 0; k < 4; ++k) {
            pb[col + k]     = a[k];
            pb[F + col + k] = a[4 + k];
        }
    }
}

template <int F>
__global__ __launch_bounds__(256) void bn_reduce_par(const float* __restrict__ part,
                                                     const float* __restrict__ gamma,
                                                     const float* __restrict__ beta,
                                                     float* __restrict__ ss,
                                                     float invN) {
    __shared__ float sd[8][33];
    const int t = threadIdx.x;
    const int pr = t >> 5;          // partial-row 0..7
    const int tg = t & 31;          // target 0..31 (0-15 sum, 16-31 sumsq)
    const int c0 = blockIdx.x * 16;
    const int col = (tg < 16) ? (c0 + tg) : (F + c0 + (tg - 16));
    float a = 0.f;
    for (int p = pr; p < BNP; p += 8)          // fixed order, coalesced
        a += part[(size_t)p * 2 * F + col];
    sd[pr][tg] = a;
    __syncthreads();
    if (pr == 0) {
        float tot = sd[0][tg];
#pragma unroll
        for (int r = 1; r < 8; ++r) tot += sd[r][tg];   // fixed serial order
        sd[0][tg] = tot;
    }
    __syncthreads();
    if (t < 16) {
        int c = c0 + t;
        float s = sd[0][t];
        float q = sd[0][16 + t];
        float mu = s * invN;
        float var = q * invN - mu * mu;
        float sc = gamma[c] * rsqrtf(var + 1e-5f);
        ss[c] = sc;
        ss[F + c] = beta[c] - mu * sc;
    }
}

__global__ void bn_apply_elu_bf16(const float* __restrict__ x, const float* __restrict__ ss,
                                  unsigned short* __restrict__ outA,
                                  int Nn, int F, int fmask) {
    long long idx4 = ((long long)blockIdx.x * blockDim.x + threadIdx.x) * 4;
    int row = (int)(idx4 / F);
    ushort4 o = make_ushort4(0, 0, 0, 0);
    if (row < Nn) {
        int c = (int)(idx4 & fmask);
        float4 v = *(const float4*)(x + idx4);
        float v0 = v.x * ss[c + 0] + ss[F + c + 0];
        float v1 = v.y * ss[c + 1] + ss[F + c + 1];
        float v2 = v.z * ss[c + 2] + ss[F + c + 2];
        float v3 = v.w * ss[c + 3] + ss[F + c + 3];
        v0 = (v0 > 0.f) ? v0 : (__expf(v0) - 1.f);
        v1 = (v1 > 0.f) ? v1 : (__expf(v1) - 1.f);
        v2 = (v2 > 0.f) ? v2 : (__expf(v2) - 1.f);
        v3 = (v3 > 0.f) ? v3 : (__expf(v3) - 1.f);
        o.x = f2bf(v0); o.y = f2bf(v1); o.z = f2bf(v2); o.w = f2bf(v3);
    }
    *(ushort4*)(outA + idx4) = o;
}

// log_softmax over 16 features per node
__global__ void log_softmax16(const float* __restrict__ x, float* __restrict__ out, int Nn) {
    int n = blockIdx.x * blockDim.x + threadIdx.x;
    if (n >= Nn) return;
    float v[16];
    float m = -1e30f;
#pragma unroll
    for (int i = 0; i < 16; ++i) { v[i] = x[n * 16 + i]; m = fmaxf(m, v[i]); }
    float s = 0.f;
#pragma unroll
    for (int i = 0; i < 16; ++i) s += __expf(v[i] - m);
    float l = __logf(s) + m;
#pragma unroll
    for (int i = 0; i < 16; ++i) out[n * 16 + i] = v[i] - l;
}

// ---------------------------------------------------------------------------
// Launcher
// ---------------------------------------------------------------------------
extern "C" void kernel_launch(void* const* d_in, const int* in_sizes, int n_in,
                              void* d_out, int out_size, void* d_ws, size_t ws_size,
                              hipStream_t stream) {
    const float* x   = (const float*)d_in[0];
    const int*   ei  = (const int*)d_in[1];
    const float* W1  = (const float*)d_in[2];
    const float* as1 = (const float*)d_in[3];
    const float* ad1 = (const float*)d_in[4];
    const float* b1  = (const float*)d_in[5];
    const float* ga1 = (const float*)d_in[6];
    const float* be1 = (const float*)d_in[7];
    const float* W2  = (const float*)d_in[8];
    const float* as2 = (const float*)d_in[9];
    const float* ad2 = (const float*)d_in[10];
    const float* b2  = (const float*)d_in[11];
    const float* ga2 = (const float*)d_in[12];
    const float* be2 = (const float*)d_in[13];
    const float* W3  = (const float*)d_in[14];
    const float* as3 = (const float*)d_in[15];
    const float* ad3 = (const float*)d_in[16];
    const float* b3  = (const float*)d_in[17];
    const float* ga3 = (const float*)d_in[18];
    const float* be3 = (const float*)d_in[19];
    const float* W4  = (const float*)d_in[20];
    const float* as4 = (const float*)d_in[21];
    const float* ad4 = (const float*)d_in[22];
    const float* b4  = (const float*)d_in[23];
    float* outp = (float*)d_out;

    uint8_t* base = (uint8_t*)d_ws;
    size_t off = 0;
    auto alloc = [&](size_t nbytes) -> void* {
        off = (off + 255) & ~(size_t)255;
        void* p = base + off;
        off += nbytes;
        return p;
    };
    float* bufO = (float*)alloc((size_t)NN * 512 * 4);                       // agg out (fp32, BN in)
    unsigned short* bufA = (unsigned short*)alloc((size_t)MPAD * 512 * 2);   // bf16 GEMM A
    unsigned short* hN   = (unsigned short*)alloc((size_t)NN * 512 * 2);     // bf16 node-major h
    unsigned short* Wt1  = (unsigned short*)alloc((size_t)512 * 512 * 2);
    unsigned short* Wt2  = (unsigned short*)alloc((size_t)256 * 512 * 2);
    unsigned short* Wt3  = (unsigned short*)alloc((size_t)128 * 256 * 2);
    float* aSn  = (float*)alloc((size_t)NN * 8 * 4);
    float* aDn  = (float*)alloc((size_t)NN * 8 * 4);
    int*   cnt  = (int*)alloc((size_t)NN * 4);
    int*   rowp = (int*)alloc((size_t)(NN + 1) * 4);
    int*   wptr = (int*)alloc((size_t)NN * 4);
    int*   colx = (int*)alloc((size_t)ET * 4);
    float* bnp  = (float*)alloc((size_t)BNP * 1024 * 4);     // BN partials [BNP][2F]
    float* bns  = (float*)alloc((size_t)1024 * 4);           // scale/shift

    const int* srcRow = ei;
    const int* dstRow = ei + EE;

    // ---- CSR build ----
    zero_i32<<<(NN + 255) / 256, 256, 0, stream>>>(cnt, NN);
    count_edges<<<(ET + 255) / 256, 256, 0, stream>>>(dstRow, cnt);
    scan20k<<<1, 1024, 0, stream>>>(cnt, rowp, wptr, NN);
    fill_edges<<<(ET + 255) / 256, 256, 0, stream>>>(srcRow, dstRow, wptr, colx);

    // ---- Weight transposes+casts (once) ----
    cvt_w_t<<<(512 * 512 + 255) / 256, 256, 0, stream>>>(W1, Wt1, 512, 512);
    cvt_w_t<<<(512 * 256 + 255) / 256, 256, 0, stream>>>(W2, Wt2, 512, 256);
    cvt_w_t<<<(256 * 128 + 255) / 256, 256, 0, stream>>>(W3, Wt3, 256, 128);

    // ---- Layer 1: Fin=512, H=8, C=64 (F=512) ----
    {
        cvt_a_bf16<<<((MPAD * 512 / 4) + 255) / 256, 256, 0, stream>>>(x, bufA, NN, MPAD, 512);
        dim3 g(512 / 128, MPAD / 128);
        gemm_bf16_fused<<<g, 256, 0, stream>>>(bufA, Wt1, hN, aSn, aDn, as1, ad1, NN, 512, 512);
        gat_agg_all<8><<<NN / 4, 256, 0, stream>>>(hN, aSn, aDn, rowp, colx, b1, bufO, NN);
        bn_stats_det<512><<<BNP, 256, 0, stream>>>(bufO, bnp, (long long)NN * 512);
        bn_reduce_par<512><<<512 / 16, 256, 0, stream>>>(bnp, ga1, be1, bns, 1.0f / NN);
        bn_apply_elu_bf16<<<(MPAD * 512 / 4) / 256, 256, 0, stream>>>(bufO, bns, bufA, NN, 512, 511);
    }
    // ---- Layer 2: Fin=512, H=4, C=64 (F=256) ----
    {
        dim3 g(256 / 128, MPAD / 128);
        gemm_bf16_fused<<<g, 256, 0, stream>>>(bufA, Wt2, hN, aSn, aDn, as2, ad2, NN, 256, 512);
        gat_agg_all<4><<<NN / 4, 256, 0, stream>>>(hN, aSn, aDn, rowp, colx, b2, bufO, NN);
        bn_stats_det<256><<<BNP, 256, 0, stream>>>(bufO, bnp, (long long)NN * 256);
        bn_reduce_par<256><<<256 / 16, 256, 0, stream>>>(bnp, ga2, be2, bns, 1.0f / NN);
        bn_apply_elu_bf16<<<(MPAD * 256 / 4) / 256, 256, 0, stream>>>(bufO, bns, bufA, NN, 256, 255);
    }
    // ---- Layer 3: Fin=256, H=2, C=64 (F=128) ----
    {
        dim3 g(128 / 128, MPAD / 128);
        gemm_bf16_fused<<<g, 256, 0, stream>>>(bufA, Wt3, hN, aSn, aDn, as3, ad3, NN, 128, 256);
        gat_agg_all<2><<<NN / 4, 256, 0, stream>>>(hN, aSn, aDn, rowp, colx, b3, bufO, NN);
        bn_stats_det<128><<<BNP, 256, 0, stream>>>(bufO, bnp, (long long)NN * 128);
        bn_reduce_par<128><<<128 / 16, 256, 0, stream>>>(bnp, ga3, be3, bns, 1.0f / NN);
        bn_apply_elu_bf16<<<(MPAD * 128 / 4) / 256, 256, 0, stream>>>(bufO, bns, bufA, NN, 128, 127);
    }
    // ---- Layer 4: Fin=128, H=1, C=16 (F=16) + log_softmax ----
    {
        bf2f_kernel<<<(int)(((long long)NN * 128 / 4 + 255) / 256), 256, 0, stream>>>(
            bufA, bufO, (long long)NN * 128);
        dim3 g((16 + 63) / 64, (NN + 63) / 64);
        gemm_f32_bf16out<<<g, 256, 0, stream>>>(bufO, W4, hN, NN, 16, 128);
        att_scores_bf<16><<<(NN + 3) / 4, 256, 0, stream>>>(hN, as4, ad4, aSn, aDn, NN);
        gat_agg_bf<1, 16><<<NN / 4, 256, 0, stream>>>(hN, aSn, aDn, rowp, colx, b4, bufO, NN);
        log_softmax16<<<(NN + 255) / 256, 256, 0, stream>>>(bufO, outp, NN);
    }
}